// Round 7
// baseline (991.726 us; speedup 1.0000x reference)
//
#include <hip/hip_runtime.h>
#include <stdint.h>

typedef __bf16 bf16;
typedef __bf16 bf16x8 __attribute__((ext_vector_type(8)));
typedef float f32x4 __attribute__((ext_vector_type(4)));

typedef const uint32_t __attribute__((address_space(1))) guint_t;
typedef uint32_t __attribute__((address_space(3))) luint_t;

__device__ __forceinline__ void gload_lds16(const void* g, void* l) {
  __builtin_amdgcn_global_load_lds((guint_t*)g, (luint_t*)l, 16, 0, 0);
}

// ---------------------------------------------------------------- weight prep
struct OctTab { int J[64]; float SG[64]; };
struct Ptr7 { const float* p[7]; int opsz[7]; };

__global__ __launch_bounds__(256) void scales_kernel(Ptr7 t, float* __restrict__ scales) {
  int bx = blockIdx.x;
  int ti = bx >> 3, i = bx & 7;
  int n = t.opsz[ti];
  const float4* base = (const float4*)(t.p[ti] + (size_t)i * n);
  int n4 = n >> 2;
  float s = 0.f;
  for (int j = threadIdx.x; j < n4; j += 256) {
    float4 v = base[j];
    s += fabsf(v.x) + fabsf(v.y) + fabsf(v.z) + fabsf(v.w);
  }
#pragma unroll
  for (int off = 32; off >= 1; off >>= 1) s += __shfl_xor(s, off);
  __shared__ float red[4];
  int lane = threadIdx.x & 63, wvi = threadIdx.x >> 6;
  if (lane == 0) red[wvi] = s;
  __syncthreads();
  if (threadIdx.x == 0) scales[bx] = (red[0] + red[1] + red[2] + red[3]) / (float)n;
}

// Dense expansion: Wt[(rowOff + k*O + o)*ld + J[k,i]*P + p] = SG[k,i]*quant(W[i,o,p])
__global__ __launch_bounds__(256) void build_dense_kernel(
    const float* __restrict__ W, const float* __restrict__ scales,
    bf16* __restrict__ Wt, int O, int P, int ld, int rowOff, int total, OctTab tab) {
  int idx = blockIdx.x * 256 + threadIdx.x;
  if (idx >= total) return;
  int p = idx % P;
  int rest = idx / P;
  int o = rest % O;
  rest /= O;
  int i = rest & 7;
  int k = rest >> 3;
  float s = scales[i];
  float w = W[((size_t)i * O + o) * P + p];
  float q = rintf(w / (s + 1e-8f));
  q = fminf(1.f, fmaxf(-1.f, q)) * s;
  int j = tab.J[k * 8 + i];
  float sg = tab.SG[k * 8 + i];
  Wt[(size_t)(rowOff + k * O + o) * ld + j * P + p] = (bf16)(sg * q);
}

// zero K-pad columns 5464..5503 of Wd (2048 rows, ld 5504)
__global__ __launch_bounds__(256) void zero_pad_kernel(bf16* __restrict__ Wd) {
  int idx = blockIdx.x * 256 + threadIdx.x;  // 2048*40 = 81920
  if (idx >= 81920) return;
  int row = idx / 40, c = idx % 40;
  Wd[(size_t)row * 5504 + 5464 + c] = (bf16)0.f;
}

// ---------------------------------------------------------------- rmsnorm (f32 in -> bf16 out)
__global__ __launch_bounds__(256) void rmsnorm_kernel(
    const float* __restrict__ x, const float* __restrict__ w, bf16* __restrict__ out) {
  int row = blockIdx.x;
  int tid = threadIdx.x;
  const float4* xp = (const float4*)(x + (size_t)row * 2048);
  float4 a = xp[tid * 2], b = xp[tid * 2 + 1];
  float ss = a.x*a.x + a.y*a.y + a.z*a.z + a.w*a.w
           + b.x*b.x + b.y*b.y + b.z*b.z + b.w*b.w;
#pragma unroll
  for (int off = 32; off >= 1; off >>= 1) ss += __shfl_xor(ss, off);
  __shared__ float red[4];
  int lane = tid & 63, wvi = tid >> 6;
  if (lane == 0) red[wvi] = ss;
  __syncthreads();
  float tot = red[0] + red[1] + red[2] + red[3];
  float rms = rsqrtf(tot * (1.f / 2048.f) + 1e-6f);
  const float4* wp = (const float4*)w;
  float4 wa = wp[tid * 2], wb = wp[tid * 2 + 1];
  bf16x8 ov;
  ov[0] = (bf16)(a.x * rms * wa.x); ov[1] = (bf16)(a.y * rms * wa.y);
  ov[2] = (bf16)(a.z * rms * wa.z); ov[3] = (bf16)(a.w * rms * wa.w);
  ov[4] = (bf16)(b.x * rms * wb.x); ov[5] = (bf16)(b.y * rms * wb.y);
  ov[6] = (bf16)(b.z * rms * wb.z); ov[7] = (bf16)(b.w * rms * wb.w);
  *(bf16x8*)(out + (size_t)row * 2048 + tid * 8) = ov;
}

// ---------------------------------------------------------------- GEMM  C = A(MxK) * Bt(NxK)^T
// BM x 256 tile, 8 waves (2M x 4N), BK=64, 16x16x32 bf16 MFMA, depth-2 LDS double-buffer.
// R3-PROVEN schedule: burst-STAGE tile kt+1 at iteration top, then counted s_waitcnt vmcnt(TC)
// (tile kt's TC loads landed; kt+1's TC stay in flight), raw s_barrier, then 4 phases of
// {ds_read frags | barrier | setprio(1) MFMA setprio(0) | barrier}. Both-sides XOR swizzle (T2),
// bijective XCD swizzle (T1). Store guarded by col<Nst for padded-N.
// MODE 0: bf16 store.  MODE 1: f32 store + f32 residual add.
// SIGNATURE: (A, Bt, res, Cout, K, Nst, ldC)  -- K is arg 5! (R5/R6 bug: K/N transposed at call site)
template <int BM, int MODE>
__global__ __launch_bounds__(512, 2) void gemm_tile(
    const bf16* __restrict__ A, const bf16* __restrict__ Bt,
    const float* __restrict__ res, void* __restrict__ Cout,
    int K, int Nst, int ldC) {
  constexpr int ABYTES = BM * 128;            // one A buffer (BM rows x 64 bf16)
  constexpr int ACH = BM / 64;                // A chunks per wave (1KB each)
  constexpr int TC  = ACH + 4;                // loads issued per tile per wave
  constexpr int MF  = BM / 32;                // per-wave M fragments
  constexpr int MFP = MF / 4;                 // M fragments per phase
  __shared__ char smem[2 * ABYTES + 65536];   // [A0][A1][B0][B1]
  const int tid = threadIdx.x;
  const int lane = tid & 63, wave = tid >> 6;
  int nwg = gridDim.x * gridDim.y;
  int lin = blockIdx.y * gridDim.x + blockIdx.x;
  if ((nwg & 7) == 0) lin = (lin & 7) * (nwg >> 3) + (lin >> 3);
  const int bm = (lin / gridDim.x) * BM;
  const int bn = (lin % gridDim.x) * 256;
  const int wm = wave >> 2, wn = wave & 3;    // 2 x 4 wave grid
  const int r = lane & 15, g = lane >> 4;
  const int srow = lane >> 3, sslot = lane & 7;

  f32x4 acc[MF][4] = {};
  const int nkt = K >> 6;

  auto STAGE = [&](int kt, int buf) {
    int k0 = kt << 6;
#pragma unroll
    for (int c = 0; c < ACH; ++c) {
      int ca = wave * ACH + c;
      int row = ca * 8 + srow;
      int sc = ((sslot ^ (row & 7)) << 3);    // pre-swizzled global source col (bf16 elems)
      gload_lds16(A + (size_t)(bm + row) * K + k0 + sc,
                  smem + buf * ABYTES + ca * 1024);
    }
#pragma unroll
    for (int c = 0; c < 4; ++c) {
      int cb = wave * 4 + c;
      int row = cb * 8 + srow;
      int sc = ((sslot ^ (row & 7)) << 3);
      gload_lds16(Bt + (size_t)(bn + row) * K + k0 + sc,
                  smem + 2 * ABYTES + buf * 32768 + cb * 1024);
    }
  };

  STAGE(0, 0);
  int cur = 0;
  for (int kt = 0; kt < nkt; ++kt) {
    if (kt + 1 < nkt) {
      STAGE(kt + 1, cur ^ 1);
      if constexpr (TC == 8) asm volatile("s_waitcnt vmcnt(8)" ::: "memory");
      else                   asm volatile("s_waitcnt vmcnt(6)" ::: "memory");
    } else {
      asm volatile("s_waitcnt vmcnt(0)" ::: "memory");
    }
    __builtin_amdgcn_s_barrier();
    const char* ab = smem + cur * ABYTES;
    const char* bb = smem + 2 * ABYTES + cur * 32768;
    bf16x8 bfr[4][2];
#pragma unroll
    for (int p = 0; p < 4; ++p) {
      if (p == 0) {
#pragma unroll
        for (int n = 0; n < 4; ++n)
#pragma unroll
          for (int kk = 0; kk < 2; ++kk) {
            int rown = wn * 64 + n * 16 + r;
            int cc = (kk * 4 + g) ^ (rown & 7);
            bfr[n][kk] = *(const bf16x8*)(bb + rown * 128 + cc * 16);
          }
      }
      bf16x8 af[MFP][2];
#pragma unroll
      for (int q = 0; q < MFP; ++q)
#pragma unroll
        for (int kk = 0; kk < 2; ++kk) {
          int rowm = wm * (BM / 2) + (p * MFP + q) * 16 + r;
          int cc = (kk * 4 + g) ^ (rowm & 7);
          af[q][kk] = *(const bf16x8*)(ab + rowm * 128 + cc * 16);
        }
      __builtin_amdgcn_s_barrier();     // phase fence (scheduling; reads from stable buffer)
      __builtin_amdgcn_s_setprio(1);
#pragma unroll
      for (int q = 0; q < MFP; ++q)
#pragma unroll
        for (int n = 0; n < 4; ++n)
#pragma unroll
          for (int kk = 0; kk < 2; ++kk)
            acc[p * MFP + q][n] = __builtin_amdgcn_mfma_f32_16x16x32_bf16(
                af[q][kk], bfr[n][kk], acc[p * MFP + q][n], 0, 0, 0);
      __builtin_amdgcn_s_setprio(0);
      __builtin_amdgcn_s_barrier();     // all waves done reading before next overwrite window
    }
    cur ^= 1;
  }
#pragma unroll
  for (int mf = 0; mf < MF; ++mf) {
    int row0 = bm + wm * (BM / 2) + mf * 16 + g * 4;
#pragma unroll
    for (int nf = 0; nf < 4; ++nf) {
      int col = bn + wn * 64 + nf * 16 + r;
      if (col < Nst) {
#pragma unroll
        for (int j = 0; j < 4; ++j) {
          size_t off = (size_t)(row0 + j) * ldC + col;
          if (MODE == 0) ((bf16*)Cout)[off] = (bf16)acc[mf][nf][j];
          else           ((float*)Cout)[off] = acc[mf][nf][j] + res[off];
        }
      }
    }
  }
}

// ---------------------------------------------------------------- RoPE in-place on q,k halves of qkv
__global__ __launch_bounds__(256) void rope_kernel(
    bf16* __restrict__ qkv, const float* __restrict__ fc, const float* __restrict__ fs) {
  int tid = blockIdx.x * 256 + threadIdx.x;
  int ub = tid & 15;
  int h = (tid >> 4) & 15;
  int qk = (tid >> 8) & 1;
  int row = tid >> 9;
  int t = row & 1023;
  bf16* p = qkv + (size_t)row * 6144 + qk * 2048 + h * 128 + ub * 8;
  bf16x8 v = *(bf16x8*)p;
  const float4 cv = *(const float4*)(fc + t * 64 + ub * 4);
  const float4 sv = *(const float4*)(fs + t * 64 + ub * 4);
  float cr[4] = {cv.x, cv.y, cv.z, cv.w};
  float sr[4] = {sv.x, sv.y, sv.z, sv.w};
  bf16x8 ov;
#pragma unroll
  for (int u = 0; u < 4; ++u) {
    float xr = (float)v[2 * u], xi = (float)v[2 * u + 1];
    ov[2 * u]     = (bf16)(xr * cr[u] - xi * sr[u]);
    ov[2 * u + 1] = (bf16)(xr * sr[u] + xi * cr[u]);
  }
  *(bf16x8*)p = ov;
}

// ---------------------------------------------------------------- flash attention (causal)
// grid (64 bh, 16 qtiles), 256 thr. Wave = 16 q-rows; kv chunks of 32.
// Vt unit-level XOR swizzle (write 16-way conflict fix, round-3 verified).
__global__ __launch_bounds__(256) void attn_kernel(
    const bf16* __restrict__ qkv, bf16* __restrict__ y) {
  __shared__ bf16 Vt[128][40];
  __shared__ bf16 P[4][16][40];
  int tid = threadIdx.x;
  int lane = tid & 63, wvi = tid >> 6;
  int bh = blockIdx.x, qt = blockIdx.y;
  int b = bh >> 4, h = bh & 15;
  int q0 = qt * 64;
  int r = lane & 15, g = lane >> 4;
  const bf16* base = qkv + (size_t)b * 1024 * 6144;
  bf16x8 qf[4];
  {
    const bf16* qp = base + (size_t)(q0 + wvi * 16 + r) * 6144 + h * 128 + g * 8;
#pragma unroll
    for (int kk = 0; kk < 4; ++kk) qf[kk] = *(const bf16x8*)(qp + kk * 32);
  }
  f32x4 o[8];
#pragma unroll
  for (int d = 0; d < 8; ++d) o[d] = (f32x4){0.f, 0.f, 0.f, 0.f};
  float m_run[4], l_run[4];
#pragma unroll
  for (int j = 0; j < 4; ++j) { m_run[j] = -1e30f; l_run[j] = 0.f; }
  const float sc = 0.08838834764831845f; // 1/sqrt(128)
  int nch = (q0 >> 5) + 2;
  for (int c = 0; c < nch; ++c) {
    __syncthreads();
#pragma unroll
    for (int it = 0; it < 2; ++it) {  // stage V chunk transposed (swizzled units)
      int e = it * 256 + tid;
      int vr = e >> 4, dg = e & 15;
      bf16x8 vvv = *(const bf16x8*)(base + (size_t)(c * 32 + vr) * 6144 + 4096 + h * 128 + dg * 8);
      int ub = vr >> 3, uo = vr & 7;
#pragma unroll
      for (int u = 0; u < 8; ++u) {
        int R = dg * 8 + u;
        Vt[R][((ub ^ ((R >> 3) & 3)) << 3) + uo] = vvv[u];
      }
    }
    __syncthreads();
    f32x4 s0 = {0, 0, 0, 0}, s1 = {0, 0, 0, 0};
    const bf16* kp = base + (size_t)(c * 32 + r) * 6144 + 2048 + h * 128 + g * 8;
#pragma unroll
    for (int kk = 0; kk < 4; ++kk) {
      bf16x8 kf0 = *(const bf16x8*)(kp + kk * 32);
      bf16x8 kf1 = *(const bf16x8*)(kp + (size_t)16 * 6144 + kk * 32);
      s0 = __builtin_amdgcn_mfma_f32_16x16x32_bf16(qf[kk], kf0, s0, 0, 0, 0);
      s1 = __builtin_amdgcn_mfma_f32_16x16x32_bf16(qf[kk], kf1, s1, 0, 0, 0);
    }
    int qrow = q0 + wvi * 16 + g * 4;
    int kc = c * 32 + r;
    float pmax[4];
#pragma unroll
    for (int j = 0; j < 4; ++j) {
      float a0 = s0[j] * sc, a1 = s1[j] * sc;
      if (kc > qrow + j) a0 = -1e30f;
      if (kc + 16 > qrow + j) a1 = -1e30f;
      s0[j] = a0; s1[j] = a1;
      pmax[j] = fmaxf(a0, a1);
    }
#pragma unroll
    for (int j = 0; j < 4; ++j) {
#pragma unroll
      for (int w = 8; w >= 1; w >>= 1) pmax[j] = fmaxf(pmax[j], __shfl_xor(pmax[j], w));
    }
    float corr[4], rsum[4];
#pragma unroll
    for (int j = 0; j < 4; ++j) {
      float nm = fmaxf(m_run[j], pmax[j]);
      corr[j] = __expf(m_run[j] - nm);
      m_run[j] = nm;
      float p0 = __expf(s0[j] - nm), p1 = __expf(s1[j] - nm);
      s0[j] = p0; s1[j] = p1;
      rsum[j] = p0 + p1;
    }
#pragma unroll
    for (int j = 0; j < 4; ++j) {
#pragma unroll
      for (int w = 8; w >= 1; w >>= 1) rsum[j] += __shfl_xor(rsum[j], w);
      l_run[j] = l_run[j] * corr[j] + rsum[j];
      P[wvi][g * 4 + j][r] = (bf16)s0[j];
      P[wvi][g * 4 + j][16 + r] = (bf16)s1[j];
    }
#pragma unroll
    for (int d = 0; d < 8; ++d)
#pragma unroll
      for (int j = 0; j < 4; ++j) o[d][j] *= corr[j];
    asm volatile("s_waitcnt lgkmcnt(0)" ::: "memory");
    bf16x8 pa = *(const bf16x8*)&P[wvi][r][g * 8];
#pragma unroll
    for (int d = 0; d < 8; ++d) {
      int R = d * 16 + r;
      bf16x8 vb = *(const bf16x8*)&Vt[R][(g ^ ((R >> 3) & 3)) << 3];
      o[d] = __builtin_amdgcn_mfma_f32_16x16x32_bf16(pa, vb, o[d], 0, 0, 0);
    }
  }
#pragma unroll
  for (int j = 0; j < 4; ++j) {
    float inv = 1.f / l_run[j];
    size_t row = (size_t)(b * 1024 + q0 + wvi * 16 + g * 4 + j);
    bf16* yp = y + row * 2048 + h * 128 + r;
#pragma unroll
    for (int d = 0; d < 8; ++d) yp[d * 16] = (bf16)(o[d][j] * inv);
  }
}

// ---------------------------------------------------------------- silu(gate)*up -> act (in-place over gate)
__global__ __launch_bounds__(256) void silu_kernel(
    const bf16* __restrict__ up, bf16* __restrict__ gate_act) {
  int tid = blockIdx.x * 256 + threadIdx.x;
  int jb = tid % 688;
  int row = tid / 688;
  size_t off = (size_t)row * 5504 + jb * 8;
  bf16x8 ov;
  if (jb < 683) {
    bf16x8 gv = *(const bf16x8*)(gate_act + off);
    bf16x8 uv = *(const bf16x8*)(up + off);
#pragma unroll
    for (int u = 0; u < 8; ++u) {
      float gg = (float)gv[u], uu = (float)uv[u];
      ov[u] = (bf16)(gg / (1.f + __expf(-gg)) * uu);
    }
  } else {
#pragma unroll
    for (int u = 0; u < 8; ++u) ov[u] = (bf16)0.f;  // zero K-pad cols 5464..5503
  }
  *(bf16x8*)(gate_act + off) = ov;
}

// ---------------------------------------------------------------- host
static void build_oct(OctTab& t) {
  int idx[8][8]; float sgn[8][8];
  for (int j = 0; j < 8; ++j) { idx[0][j] = j; sgn[0][j] = 1.f; }
  for (int i = 1; i < 8; ++i) {
    idx[i][0] = i; sgn[i][0] = 1.f;
    idx[i][i] = 0; sgn[i][i] = -1.f;
  }
  const int tr[7][3] = {{1,2,3},{1,4,5},{1,7,6},{2,4,6},{2,5,7},{3,4,7},{3,6,5}};
  for (int ti = 0; ti < 7; ++ti) {
    int a = tr[ti][0], b = tr[ti][1], c = tr[ti][2];
    int cyc[3][3] = {{a,b,c},{b,c,a},{c,a,b}};
    for (int ci = 0; ci < 3; ++ci) {
      int p = cyc[ci][0], q = cyc[ci][1], r = cyc[ci][2];
      idx[p][q] = r; sgn[p][q] = 1.f;
      idx[q][p] = r; sgn[q][p] = -1.f;
    }
  }
  for (int i = 0; i < 8; ++i)
    for (int j = 0; j < 8; ++j) {
      int k = idx[i][j];
      t.J[k * 8 + i] = j;
      t.SG[k * 8 + i] = sgn[i][j];
    }
}

// workspace layout (bytes), aliased:
#define OFF_SCALES 0ull
#define OFF_WBUF   256ull
#define OFF_R16    (OFF_WBUF + 25165824ull)   // max weight = Wqkv 6144x2048 bf16
#define OFF_QKVR   (OFF_R16 + 16777216ull)
#define OFF_H      (OFF_QKVR + 50331648ull)
#define OFF_G1     (OFF_H + 33554432ull)
#define WS_NEED    (OFF_G1 + 45088768ull)     // ~163 MB

extern "C" void kernel_launch(void* const* d_in, const int* in_sizes, int n_in,
                              void* d_out, int out_size, void* d_ws, size_t ws_size,
                              hipStream_t stream) {
  (void)in_sizes; (void)n_in; (void)out_size;
  if (ws_size < WS_NEED) return;

  const float* x   = (const float*)d_in[0];
  const float* fc  = (const float*)d_in[1];
  const float* fs  = (const float*)d_in[2];
  const float* anw = (const float*)d_in[3];
  const float* fnw = (const float*)d_in[4];
  const float* wqw = (const float*)d_in[5];
  const float* wkw = (const float*)d_in[6];
  const float* wvw = (const float*)d_in[7];
  const float* wow = (const float*)d_in[8];
  const float* wgw = (const float*)d_in[9];
  const float* wuw = (const float*)d_in[10];
  const float* wdw = (const float*)d_in[11];

  char* ws = (char*)d_ws;
  float* scales = (float*)(ws + OFF_SCALES);
  bf16* Wbuf = (bf16*)(ws + OFF_WBUF);
  bf16* xn   = (bf16*)(ws + OFF_R16);   // then y, then hn
  bf16* qkv  = (bf16*)(ws + OFF_QKVR);  // then up
  float* h   = (float*)(ws + OFF_H);
  bf16* g1   = (bf16*)(ws + OFF_G1);    // gate, then act in-place

  OctTab tab; build_oct(tab);
  Ptr7 p7;
  p7.p[0] = wqw; p7.p[1] = wkw; p7.p[2] = wvw; p7.p[3] = wow;
  p7.p[4] = wgw; p7.p[5] = wuw; p7.p[6] = wdw;
  for (int i = 0; i < 4; ++i) p7.opsz[i] = 65536;
  for (int i = 4; i < 7; ++i) p7.opsz[i] = 174848;

  scales_kernel<<<56, 256, 0, stream>>>(p7, scales);

  // ---- QKV: build fused [Wq;Wk;Wv] (6144x2048), gemm, rope, attention
  build_dense_kernel<<<16384, 256, 0, stream>>>(wqw, scales + 0,  Wbuf, 256, 256, 2048, 0,    4194304, tab);
  build_dense_kernel<<<16384, 256, 0, stream>>>(wkw, scales + 8,  Wbuf, 256, 256, 2048, 2048, 4194304, tab);
  build_dense_kernel<<<16384, 256, 0, stream>>>(wvw, scales + 16, Wbuf, 256, 256, 2048, 4096, 4194304, tab);
  rmsnorm_kernel<<<4096, 256, 0, stream>>>(x, anw, xn);
  gemm_tile<256, 0><<<dim3(24, 16), 512, 0, stream>>>(xn, Wbuf, nullptr, qkv, 2048, 6144, 6144);
  rope_kernel<<<8192, 256, 0, stream>>>(qkv, fc, fs);
  attn_kernel<<<dim3(64, 16), 256, 0, stream>>>(qkv, (bf16*)(ws + OFF_R16) /* y over xn */);

  // ---- O-proj + residual (f32): 128x256 tile, grid 8x32 = 256 blocks (tail-free). K=2048.
  build_dense_kernel<<<16384, 256, 0, stream>>>(wow, scales + 24, Wbuf, 256, 256, 2048, 0, 4194304, tab);
  gemm_tile<128, 1><<<dim3(8, 32), 512, 0, stream>>>((bf16*)(ws + OFF_R16), Wbuf, x, h, 2048, 2048, 2048);

  // ---- FFN
  bf16* hn = (bf16*)(ws + OFF_R16);  // overwrite y (dead)
  rmsnorm_kernel<<<4096, 256, 0, stream>>>(h, fnw, hn);
  // gate: build Wg (5464 rows in 5504-row region), gemm N-guard 5504 -> g1
  build_dense_kernel<<<43712, 256, 0, stream>>>(wgw, scales + 32, Wbuf, 683, 256, 2048, 0, 11190272, tab);
  gemm_tile<256, 0><<<dim3(22, 16), 512, 0, stream>>>(hn, Wbuf, nullptr, g1, 2048, 5504, 5504);
  // up: rebuild Wbuf, gemm -> qkv region (dead)
  bf16* up = (bf16*)(ws + OFF_QKVR);
  build_dense_kernel<<<43712, 256, 0, stream>>>(wuw, scales + 40, Wbuf, 683, 256, 2048, 0, 11190272, tab);
  gemm_tile<256, 0><<<dim3(22, 16), 512, 0, stream>>>(hn, Wbuf, nullptr, up, 2048, 5504, 5504);
  // silu(gate)*up -> act (in-place over gate), zeroing K-pad cols
  silu_kernel<<<11008, 256, 0, stream>>>(up, g1);
  // down: build Wd (2048x5504, zero the 40 pad cols), 128x256 tile + residual -> out
  // *** K=5504, Nst=2048 (R5/R6 had these transposed -> truncated reduction) ***
  build_dense_kernel<<<43712, 256, 0, stream>>>(wdw, scales + 48, Wbuf, 256, 683, 5504, 0, 11190272, tab);
  zero_pad_kernel<<<320, 256, 0, stream>>>(Wbuf);
  gemm_tile<128, 1><<<dim3(8, 32), 512, 0, stream>>>(g1, Wbuf, h, (float*)d_out, 5504, 2048, 2048);
}

// Round 8
// 925.990 us; speedup vs baseline: 1.0710x; 1.0710x over previous
//
#include <hip/hip_runtime.h>
#include <stdint.h>

typedef __bf16 bf16;
typedef __bf16 bf16x8 __attribute__((ext_vector_type(8)));
typedef float f32x4 __attribute__((ext_vector_type(4)));

typedef const uint32_t __attribute__((address_space(1))) guint_t;
typedef uint32_t __attribute__((address_space(3))) luint_t;

__device__ __forceinline__ void gload_lds16(const void* g, void* l) {
  __builtin_amdgcn_global_load_lds((guint_t*)g, (luint_t*)l, 16, 0, 0);
}

// ---------------------------------------------------------------- weight prep
struct OctTab { int J[64]; float SG[64]; };
struct Ptr7 { const float* p[7]; int opsz[7]; };

__global__ void scales_zero(float* __restrict__ scales) {
  if (threadIdx.x < 56) scales[threadIdx.x] = 0.f;
}

// 448 blocks: 8 partials per (tensor,i) slice, atomicAdd of sum|W| (mean applied in build via inv_n)
__global__ __launch_bounds__(256) void scales_partial(Ptr7 t, float* __restrict__ scales) {
  int bx = blockIdx.x;
  int part = bx & 7, sl = bx >> 3;
  int ti = sl >> 3, i = sl & 7;
  int n = t.opsz[ti];
  int n4 = n >> 2, seg = n4 >> 3;
  const float4* base = (const float4*)(t.p[ti] + (size_t)i * n) + part * seg;
  float s = 0.f;
  for (int j = threadIdx.x; j < seg; j += 256) {
    float4 v = base[j];
    s += fabsf(v.x) + fabsf(v.y) + fabsf(v.z) + fabsf(v.w);
  }
#pragma unroll
  for (int off = 32; off >= 1; off >>= 1) s += __shfl_xor(s, off);
  __shared__ float red[4];
  int lane = threadIdx.x & 63, wvi = threadIdx.x >> 6;
  if (lane == 0) red[wvi] = s;
  __syncthreads();
  if (threadIdx.x == 0) atomicAdd(&scales[sl], red[0] + red[1] + red[2] + red[3]);
}

// Dense expansion: Wt[(rowOff + k*O + o)*ld + J[k,i]*P + p] = SG[k,i]*quant(W[i,o,p])
// scales[] holds SUMS; s = scales[i] * inv_n.
__global__ __launch_bounds__(256) void build_dense_kernel(
    const float* __restrict__ W, const float* __restrict__ scales, float inv_n,
    bf16* __restrict__ Wt, int O, int P, int ld, int rowOff, int total, OctTab tab) {
  int idx = blockIdx.x * 256 + threadIdx.x;
  if (idx >= total) return;
  int p = idx % P;
  int rest = idx / P;
  int o = rest % O;
  rest /= O;
  int i = rest & 7;
  int k = rest >> 3;
  float s = scales[i] * inv_n;
  float w = W[((size_t)i * O + o) * P + p];
  float q = rintf(w / (s + 1e-8f));
  q = fminf(1.f, fmaxf(-1.f, q)) * s;
  int j = tab.J[k * 8 + i];
  float sg = tab.SG[k * 8 + i];
  Wt[(size_t)(rowOff + k * O + o) * ld + j * P + p] = (bf16)(sg * q);
}

// zero K-pad columns 5464..5503 of Wd (2048 rows, ld 5504)
__global__ __launch_bounds__(256) void zero_pad_kernel(bf16* __restrict__ Wd) {
  int idx = blockIdx.x * 256 + threadIdx.x;  // 2048*40 = 81920
  if (idx >= 81920) return;
  int row = idx / 40, c = idx % 40;
  Wd[(size_t)row * 5504 + 5464 + c] = (bf16)0.f;
}

// ---------------------------------------------------------------- rmsnorm (f32 in -> bf16 out)
__global__ __launch_bounds__(256) void rmsnorm_kernel(
    const float* __restrict__ x, const float* __restrict__ w, bf16* __restrict__ out) {
  int row = blockIdx.x;
  int tid = threadIdx.x;
  const float4* xp = (const float4*)(x + (size_t)row * 2048);
  float4 a = xp[tid * 2], b = xp[tid * 2 + 1];
  float ss = a.x*a.x + a.y*a.y + a.z*a.z + a.w*a.w
           + b.x*b.x + b.y*b.y + b.z*b.z + b.w*b.w;
#pragma unroll
  for (int off = 32; off >= 1; off >>= 1) ss += __shfl_xor(ss, off);
  __shared__ float red[4];
  int lane = tid & 63, wvi = tid >> 6;
  if (lane == 0) red[wvi] = ss;
  __syncthreads();
  float tot = red[0] + red[1] + red[2] + red[3];
  float rms = rsqrtf(tot * (1.f / 2048.f) + 1e-6f);
  const float4* wp = (const float4*)w;
  float4 wa = wp[tid * 2], wb = wp[tid * 2 + 1];
  bf16x8 ov;
  ov[0] = (bf16)(a.x * rms * wa.x); ov[1] = (bf16)(a.y * rms * wa.y);
  ov[2] = (bf16)(a.z * rms * wa.z); ov[3] = (bf16)(a.w * rms * wa.w);
  ov[4] = (bf16)(b.x * rms * wb.x); ov[5] = (bf16)(b.y * rms * wb.y);
  ov[6] = (bf16)(b.z * rms * wb.z); ov[7] = (bf16)(b.w * rms * wb.w);
  *(bf16x8*)(out + (size_t)row * 2048 + tid * 8) = ov;
}

// ---------------------------------------------------------------- GEMM  C = A(MxK) * Bt(NxK)^T
// BM x 256 tile, 8 waves (2M x 4N), BK=64, 16x16x32 bf16 MFMA, depth-2 LDS double-buffer.
// R3-PROVEN schedule: burst-STAGE tile kt+1 at iteration top, counted s_waitcnt vmcnt(TC),
// raw s_barrier, 4 phases of {ds_read | barrier | setprio(1) MFMA setprio(0) | barrier}.
// Both-sides XOR swizzle (T2), bijective XCD swizzle (T1). Store guarded by col<Nst.
// MODE 0: bf16 store.  MODE 1: f32 store + f32 residual add.
// SIGNATURE: (A, Bt, res, Cout, K, Nst, ldC)
template <int BM, int MODE>
__global__ __launch_bounds__(512, 2) void gemm_tile(
    const bf16* __restrict__ A, const bf16* __restrict__ Bt,
    const float* __restrict__ res, void* __restrict__ Cout,
    int K, int Nst, int ldC) {
  constexpr int ABYTES = BM * 128;            // one A buffer (BM rows x 64 bf16)
  constexpr int ACH = BM / 64;                // A chunks per wave (1KB each)
  constexpr int TC  = ACH + 4;                // loads issued per tile per wave
  constexpr int MF  = BM / 32;                // per-wave M fragments
  constexpr int MFP = MF / 4;                 // M fragments per phase
  __shared__ char smem[2 * ABYTES + 65536];   // [A0][A1][B0][B1]
  const int tid = threadIdx.x;
  const int lane = tid & 63, wave = tid >> 6;
  int nwg = gridDim.x * gridDim.y;
  int lin = blockIdx.y * gridDim.x + blockIdx.x;
  if ((nwg & 7) == 0) lin = (lin & 7) * (nwg >> 3) + (lin >> 3);
  const int bm = (lin / gridDim.x) * BM;
  const int bn = (lin % gridDim.x) * 256;
  const int wm = wave >> 2, wn = wave & 3;    // 2 x 4 wave grid
  const int r = lane & 15, g = lane >> 4;
  const int srow = lane >> 3, sslot = lane & 7;

  f32x4 acc[MF][4] = {};
  const int nkt = K >> 6;

  auto STAGE = [&](int kt, int buf) {
    int k0 = kt << 6;
#pragma unroll
    for (int c = 0; c < ACH; ++c) {
      int ca = wave * ACH + c;
      int row = ca * 8 + srow;
      int sc = ((sslot ^ (row & 7)) << 3);    // pre-swizzled global source col (bf16 elems)
      gload_lds16(A + (size_t)(bm + row) * K + k0 + sc,
                  smem + buf * ABYTES + ca * 1024);
    }
#pragma unroll
    for (int c = 0; c < 4; ++c) {
      int cb = wave * 4 + c;
      int row = cb * 8 + srow;
      int sc = ((sslot ^ (row & 7)) << 3);
      gload_lds16(Bt + (size_t)(bn + row) * K + k0 + sc,
                  smem + 2 * ABYTES + buf * 32768 + cb * 1024);
    }
  };

  STAGE(0, 0);
  int cur = 0;
  for (int kt = 0; kt < nkt; ++kt) {
    if (kt + 1 < nkt) {
      STAGE(kt + 1, cur ^ 1);
      if constexpr (TC == 8) asm volatile("s_waitcnt vmcnt(8)" ::: "memory");
      else                   asm volatile("s_waitcnt vmcnt(6)" ::: "memory");
    } else {
      asm volatile("s_waitcnt vmcnt(0)" ::: "memory");
    }
    __builtin_amdgcn_s_barrier();
    const char* ab = smem + cur * ABYTES;
    const char* bb = smem + 2 * ABYTES + cur * 32768;
    bf16x8 bfr[4][2];
#pragma unroll
    for (int p = 0; p < 4; ++p) {
      if (p == 0) {
#pragma unroll
        for (int n = 0; n < 4; ++n)
#pragma unroll
          for (int kk = 0; kk < 2; ++kk) {
            int rown = wn * 64 + n * 16 + r;
            int cc = (kk * 4 + g) ^ (rown & 7);
            bfr[n][kk] = *(const bf16x8*)(bb + rown * 128 + cc * 16);
          }
      }
      bf16x8 af[MFP][2];
#pragma unroll
      for (int q = 0; q < MFP; ++q)
#pragma unroll
        for (int kk = 0; kk < 2; ++kk) {
          int rowm = wm * (BM / 2) + (p * MFP + q) * 16 + r;
          int cc = (kk * 4 + g) ^ (rowm & 7);
          af[q][kk] = *(const bf16x8*)(ab + rowm * 128 + cc * 16);
        }
      __builtin_amdgcn_s_barrier();     // phase fence (scheduling; reads from stable buffer)
      __builtin_amdgcn_s_setprio(1);
#pragma unroll
      for (int q = 0; q < MFP; ++q)
#pragma unroll
        for (int n = 0; n < 4; ++n)
#pragma unroll
          for (int kk = 0; kk < 2; ++kk)
            acc[p * MFP + q][n] = __builtin_amdgcn_mfma_f32_16x16x32_bf16(
                af[q][kk], bfr[n][kk], acc[p * MFP + q][n], 0, 0, 0);
      __builtin_amdgcn_s_setprio(0);
      __builtin_amdgcn_s_barrier();     // all waves done reading before next overwrite window
    }
    cur ^= 1;
  }
#pragma unroll
  for (int mf = 0; mf < MF; ++mf) {
    int row0 = bm + wm * (BM / 2) + mf * 16 + g * 4;
#pragma unroll
    for (int nf = 0; nf < 4; ++nf) {
      int col = bn + wn * 64 + nf * 16 + r;
      if (col < Nst) {
#pragma unroll
        for (int j = 0; j < 4; ++j) {
          size_t off = (size_t)(row0 + j) * ldC + col;
          if (MODE == 0) ((bf16*)Cout)[off] = (bf16)acc[mf][nf][j];
          else           ((float*)Cout)[off] = acc[mf][nf][j] + res[off];
        }
      }
    }
  }
}

// ---------------------------------------------------------------- RoPE in-place on q,k halves of qkv
__global__ __launch_bounds__(256) void rope_kernel(
    bf16* __restrict__ qkv, const float* __restrict__ fc, const float* __restrict__ fs) {
  int tid = blockIdx.x * 256 + threadIdx.x;
  int ub = tid & 15;
  int h = (tid >> 4) & 15;
  int qk = (tid >> 8) & 1;
  int row = tid >> 9;
  int t = row & 1023;
  bf16* p = qkv + (size_t)row * 6144 + qk * 2048 + h * 128 + ub * 8;
  bf16x8 v = *(bf16x8*)p;
  const float4 cv = *(const float4*)(fc + t * 64 + ub * 4);
  const float4 sv = *(const float4*)(fs + t * 64 + ub * 4);
  float cr[4] = {cv.x, cv.y, cv.z, cv.w};
  float sr[4] = {sv.x, sv.y, sv.z, sv.w};
  bf16x8 ov;
#pragma unroll
  for (int u = 0; u < 4; ++u) {
    float xr = (float)v[2 * u], xi = (float)v[2 * u + 1];
    ov[2 * u]     = (bf16)(xr * cr[u] - xi * sr[u]);
    ov[2 * u + 1] = (bf16)(xr * sr[u] + xi * cr[u]);
  }
  *(bf16x8*)p = ov;
}

// ---------------------------------------------------------------- flash attention (causal)
// grid (64 bh, 16 qtiles), 256 thr. Wave = 16 q-rows; kv chunks of 32.
// Vt unit-level XOR swizzle (write 16-way conflict fix, round-3 verified).
__global__ __launch_bounds__(256) void attn_kernel(
    const bf16* __restrict__ qkv, bf16* __restrict__ y) {
  __shared__ bf16 Vt[128][40];
  __shared__ bf16 P[4][16][40];
  int tid = threadIdx.x;
  int lane = tid & 63, wvi = tid >> 6;
  int bh = blockIdx.x, qt = blockIdx.y;
  int b = bh >> 4, h = bh & 15;
  int q0 = qt * 64;
  int r = lane & 15, g = lane >> 4;
  const bf16* base = qkv + (size_t)b * 1024 * 6144;
  bf16x8 qf[4];
  {
    const bf16* qp = base + (size_t)(q0 + wvi * 16 + r) * 6144 + h * 128 + g * 8;
#pragma unroll
    for (int kk = 0; kk < 4; ++kk) qf[kk] = *(const bf16x8*)(qp + kk * 32);
  }
  f32x4 o[8];
#pragma unroll
  for (int d = 0; d < 8; ++d) o[d] = (f32x4){0.f, 0.f, 0.f, 0.f};
  float m_run[4], l_run[4];
#pragma unroll
  for (int j = 0; j < 4; ++j) { m_run[j] = -1e30f; l_run[j] = 0.f; }
  const float sc = 0.08838834764831845f; // 1/sqrt(128)
  int nch = (q0 >> 5) + 2;
  for (int c = 0; c < nch; ++c) {
    __syncthreads();
#pragma unroll
    for (int it = 0; it < 2; ++it) {  // stage V chunk transposed (swizzled units)
      int e = it * 256 + tid;
      int vr = e >> 4, dg = e & 15;
      bf16x8 vvv = *(const bf16x8*)(base + (size_t)(c * 32 + vr) * 6144 + 4096 + h * 128 + dg * 8);
      int ub = vr >> 3, uo = vr & 7;
#pragma unroll
      for (int u = 0; u < 8; ++u) {
        int R = dg * 8 + u;
        Vt[R][((ub ^ ((R >> 3) & 3)) << 3) + uo] = vvv[u];
      }
    }
    __syncthreads();
    f32x4 s0 = {0, 0, 0, 0}, s1 = {0, 0, 0, 0};
    const bf16* kp = base + (size_t)(c * 32 + r) * 6144 + 2048 + h * 128 + g * 8;
#pragma unroll
    for (int kk = 0; kk < 4; ++kk) {
      bf16x8 kf0 = *(const bf16x8*)(kp + kk * 32);
      bf16x8 kf1 = *(const bf16x8*)(kp + (size_t)16 * 6144 + kk * 32);
      s0 = __builtin_amdgcn_mfma_f32_16x16x32_bf16(qf[kk], kf0, s0, 0, 0, 0);
      s1 = __builtin_amdgcn_mfma_f32_16x16x32_bf16(qf[kk], kf1, s1, 0, 0, 0);
    }
    int qrow = q0 + wvi * 16 + g * 4;
    int kc = c * 32 + r;
    float pmax[4];
#pragma unroll
    for (int j = 0; j < 4; ++j) {
      float a0 = s0[j] * sc, a1 = s1[j] * sc;
      if (kc > qrow + j) a0 = -1e30f;
      if (kc + 16 > qrow + j) a1 = -1e30f;
      s0[j] = a0; s1[j] = a1;
      pmax[j] = fmaxf(a0, a1);
    }
#pragma unroll
    for (int j = 0; j < 4; ++j) {
#pragma unroll
      for (int w = 8; w >= 1; w >>= 1) pmax[j] = fmaxf(pmax[j], __shfl_xor(pmax[j], w));
    }
    float corr[4], rsum[4];
#pragma unroll
    for (int j = 0; j < 4; ++j) {
      float nm = fmaxf(m_run[j], pmax[j]);
      corr[j] = __expf(m_run[j] - nm);
      m_run[j] = nm;
      float p0 = __expf(s0[j] - nm), p1 = __expf(s1[j] - nm);
      s0[j] = p0; s1[j] = p1;
      rsum[j] = p0 + p1;
    }
#pragma unroll
    for (int j = 0; j < 4; ++j) {
#pragma unroll
      for (int w = 8; w >= 1; w >>= 1) rsum[j] += __shfl_xor(rsum[j], w);
      l_run[j] = l_run[j] * corr[j] + rsum[j];
      P[wvi][g * 4 + j][r] = (bf16)s0[j];
      P[wvi][g * 4 + j][16 + r] = (bf16)s1[j];
    }
#pragma unroll
    for (int d = 0; d < 8; ++d)
#pragma unroll
      for (int j = 0; j < 4; ++j) o[d][j] *= corr[j];
    asm volatile("s_waitcnt lgkmcnt(0)" ::: "memory");
    bf16x8 pa = *(const bf16x8*)&P[wvi][r][g * 8];
#pragma unroll
    for (int d = 0; d < 8; ++d) {
      int R = d * 16 + r;
      bf16x8 vb = *(const bf16x8*)&Vt[R][(g ^ ((R >> 3) & 3)) << 3];
      o[d] = __builtin_amdgcn_mfma_f32_16x16x32_bf16(pa, vb, o[d], 0, 0, 0);
    }
  }
#pragma unroll
  for (int j = 0; j < 4; ++j) {
    float inv = 1.f / l_run[j];
    size_t row = (size_t)(b * 1024 + q0 + wvi * 16 + g * 4 + j);
    bf16* yp = y + row * 2048 + h * 128 + r;
#pragma unroll
    for (int d = 0; d < 8; ++d) yp[d * 16] = (bf16)(o[d][j] * inv);
  }
}

// ---------------------------------------------------------------- silu(gate)*up -> act (in-place over gate)
__global__ __launch_bounds__(256) void silu_kernel(
    const bf16* __restrict__ up, bf16* __restrict__ gate_act) {
  int tid = blockIdx.x * 256 + threadIdx.x;
  int jb = tid % 688;
  int row = tid / 688;
  size_t off = (size_t)row * 5504 + jb * 8;
  bf16x8 ov;
  if (jb < 683) {
    bf16x8 gv = *(const bf16x8*)(gate_act + off);
    bf16x8 uv = *(const bf16x8*)(up + off);
#pragma unroll
    for (int u = 0; u < 8; ++u) {
      float gg = (float)gv[u], uu = (float)uv[u];
      ov[u] = (bf16)(gg / (1.f + __expf(-gg)) * uu);
    }
  } else {
#pragma unroll
    for (int u = 0; u < 8; ++u) ov[u] = (bf16)0.f;  // zero K-pad cols 5464..5503
  }
  *(bf16x8*)(gate_act + off) = ov;
}

// ---------------------------------------------------------------- host
static void build_oct(OctTab& t) {
  int idx[8][8]; float sgn[8][8];
  for (int j = 0; j < 8; ++j) { idx[0][j] = j; sgn[0][j] = 1.f; }
  for (int i = 1; i < 8; ++i) {
    idx[i][0] = i; sgn[i][0] = 1.f;
    idx[i][i] = 0; sgn[i][i] = -1.f;
  }
  const int tr[7][3] = {{1,2,3},{1,4,5},{1,7,6},{2,4,6},{2,5,7},{3,4,7},{3,6,5}};
  for (int ti = 0; ti < 7; ++ti) {
    int a = tr[ti][0], b = tr[ti][1], c = tr[ti][2];
    int cyc[3][3] = {{a,b,c},{b,c,a},{c,a,b}};
    for (int ci = 0; ci < 3; ++ci) {
      int p = cyc[ci][0], q = cyc[ci][1], r = cyc[ci][2];
      idx[p][q] = r; sgn[p][q] = 1.f;
      idx[q][p] = r; sgn[q][p] = -1.f;
    }
  }
  for (int i = 0; i < 8; ++i)
    for (int j = 0; j < 8; ++j) {
      int k = idx[i][j];
      t.J[k * 8 + i] = j;
      t.SG[k * 8 + i] = sgn[i][j];
    }
}

// workspace layout (bytes), aliased:
#define OFF_SCALES 0ull
#define OFF_WBUF   256ull
#define OFF_R16    (OFF_WBUF + 25165824ull)   // max weight = Wqkv 6144x2048 bf16
#define OFF_QKVR   (OFF_R16 + 16777216ull)
#define OFF_H      (OFF_QKVR + 50331648ull)
#define OFF_G1     (OFF_H + 33554432ull)
#define WS_NEED    (OFF_G1 + 45088768ull)     // ~163 MB

extern "C" void kernel_launch(void* const* d_in, const int* in_sizes, int n_in,
                              void* d_out, int out_size, void* d_ws, size_t ws_size,
                              hipStream_t stream) {
  (void)in_sizes; (void)n_in; (void)out_size;
  if (ws_size < WS_NEED) return;

  const float* x   = (const float*)d_in[0];
  const float* fc  = (const float*)d_in[1];
  const float* fs  = (const float*)d_in[2];
  const float* anw = (const float*)d_in[3];
  const float* fnw = (const float*)d_in[4];
  const float* wqw = (const float*)d_in[5];
  const float* wkw = (const float*)d_in[6];
  const float* wvw = (const float*)d_in[7];
  const float* wow = (const float*)d_in[8];
  const float* wgw = (const float*)d_in[9];
  const float* wuw = (const float*)d_in[10];
  const float* wdw = (const float*)d_in[11];

  char* ws = (char*)d_ws;
  float* scales = (float*)(ws + OFF_SCALES);
  bf16* Wbuf = (bf16*)(ws + OFF_WBUF);
  bf16* xn   = (bf16*)(ws + OFF_R16);   // then y, then hn
  bf16* qkv  = (bf16*)(ws + OFF_QKVR);  // then up
  float* h   = (float*)(ws + OFF_H);
  bf16* g1   = (bf16*)(ws + OFF_G1);    // gate, then act in-place

  OctTab tab; build_oct(tab);
  Ptr7 p7;
  p7.p[0] = wqw; p7.p[1] = wkw; p7.p[2] = wvw; p7.p[3] = wow;
  p7.p[4] = wgw; p7.p[5] = wuw; p7.p[6] = wdw;
  for (int i = 0; i < 4; ++i) p7.opsz[i] = 65536;
  for (int i = 4; i < 7; ++i) p7.opsz[i] = 174848;

  const float invS = 1.f / 65536.f;   // small tensors (q,k,v,o)
  const float invL = 1.f / 174848.f;  // large tensors (gate,up,down)

  scales_zero<<<1, 64, 0, stream>>>(scales);
  scales_partial<<<448, 256, 0, stream>>>(p7, scales);

  // ---- QKV: build fused [Wq;Wk;Wv] (6144x2048), gemm, rope, attention
  build_dense_kernel<<<16384, 256, 0, stream>>>(wqw, scales + 0,  invS, Wbuf, 256, 256, 2048, 0,    4194304, tab);
  build_dense_kernel<<<16384, 256, 0, stream>>>(wkw, scales + 8,  invS, Wbuf, 256, 256, 2048, 2048, 4194304, tab);
  build_dense_kernel<<<16384, 256, 0, stream>>>(wvw, scales + 16, invS, Wbuf, 256, 256, 2048, 4096, 4194304, tab);
  rmsnorm_kernel<<<4096, 256, 0, stream>>>(x, anw, xn);
  // 128x256 tile -> grid 24x32 = 768 blocks = 3.0 tail-free rounds at 1 block/CU
  gemm_tile<128, 0><<<dim3(24, 32), 512, 0, stream>>>(xn, Wbuf, nullptr, qkv, 2048, 6144, 6144);
  rope_kernel<<<8192, 256, 0, stream>>>(qkv, fc, fs);
  attn_kernel<<<dim3(64, 16), 256, 0, stream>>>(qkv, (bf16*)(ws + OFF_R16) /* y over xn */);

  // ---- O-proj + residual (f32): 128x256 tile, grid 8x32 = 256 blocks (tail-free). K=2048.
  build_dense_kernel<<<16384, 256, 0, stream>>>(wow, scales + 24, invS, Wbuf, 256, 256, 2048, 0, 4194304, tab);
  gemm_tile<128, 1><<<dim3(8, 32), 512, 0, stream>>>((bf16*)(ws + OFF_R16), Wbuf, x, h, 2048, 2048, 2048);

  // ---- FFN
  bf16* hn = (bf16*)(ws + OFF_R16);  // overwrite y (dead)
  rmsnorm_kernel<<<4096, 256, 0, stream>>>(h, fnw, hn);
  // gate: build Wg (5464 rows in 5504-row region), 128-tile grid 22x32 = 704 blocks (2.75 rounds)
  build_dense_kernel<<<43712, 256, 0, stream>>>(wgw, scales + 32, invL, Wbuf, 683, 256, 2048, 0, 11190272, tab);
  gemm_tile<128, 0><<<dim3(22, 32), 512, 0, stream>>>(hn, Wbuf, nullptr, g1, 2048, 5504, 5504);
  // up: rebuild Wbuf, gemm -> qkv region (dead)
  bf16* up = (bf16*)(ws + OFF_QKVR);
  build_dense_kernel<<<43712, 256, 0, stream>>>(wuw, scales + 40, invL, Wbuf, 683, 256, 2048, 0, 11190272, tab);
  gemm_tile<128, 0><<<dim3(22, 32), 512, 0, stream>>>(hn, Wbuf, nullptr, up, 2048, 5504, 5504);
  // silu(gate)*up -> act (in-place over gate), zeroing K-pad cols
  silu_kernel<<<11008, 256, 0, stream>>>(up, g1);
  // down: build Wd (2048x5504, zero the 40 pad cols), 128x256 tile K=5504 + residual -> out
  build_dense_kernel<<<43712, 256, 0, stream>>>(wdw, scales + 48, invL, Wbuf, 256, 683, 5504, 0, 11190272, tab);
  zero_pad_kernel<<<320, 256, 0, stream>>>(Wbuf);
  gemm_tile<128, 1><<<dim3(8, 32), 512, 0, stream>>>(g1, Wbuf, h, (float*)d_out, 5504, 2048, 2048);
}

// Round 9
// 921.835 us; speedup vs baseline: 1.0758x; 1.0045x over previous
//
#include <hip/hip_runtime.h>
#include <stdint.h>

typedef __bf16 bf16;
typedef __bf16 bf16x8 __attribute__((ext_vector_type(8)));
typedef float f32x4 __attribute__((ext_vector_type(4)));

typedef const uint32_t __attribute__((address_space(1))) guint_t;
typedef uint32_t __attribute__((address_space(3))) luint_t;

__device__ __forceinline__ void gload_lds16(const void* g, void* l) {
  __builtin_amdgcn_global_load_lds((guint_t*)g, (luint_t*)l, 16, 0, 0);
}

// ---------------------------------------------------------------- weight prep
struct OctTab { int J[64]; float SG[64]; };
struct Ptr7 { const float* p[7]; int opsz[7]; };

__global__ void scales_zero(float* __restrict__ scales) {
  if (threadIdx.x < 56) scales[threadIdx.x] = 0.f;
}

// 448 blocks: 8 partials per (tensor,i) slice, atomicAdd of sum|W| (mean applied in build via inv_n)
__global__ __launch_bounds__(256) void scales_partial(Ptr7 t, float* __restrict__ scales) {
  int bx = blockIdx.x;
  int part = bx & 7, sl = bx >> 3;
  int ti = sl >> 3, i = sl & 7;
  int n = t.opsz[ti];
  int n4 = n >> 2, seg = n4 >> 3;
  const float4* base = (const float4*)(t.p[ti] + (size_t)i * n) + part * seg;
  float s = 0.f;
  for (int j = threadIdx.x; j < seg; j += 256) {
    float4 v = base[j];
    s += fabsf(v.x) + fabsf(v.y) + fabsf(v.z) + fabsf(v.w);
  }
#pragma unroll
  for (int off = 32; off >= 1; off >>= 1) s += __shfl_xor(s, off);
  __shared__ float red[4];
  int lane = threadIdx.x & 63, wvi = threadIdx.x >> 6;
  if (lane == 0) red[wvi] = s;
  __syncthreads();
  if (threadIdx.x == 0) atomicAdd(&scales[sl], red[0] + red[1] + red[2] + red[3]);
}

// Dense expansion: Wt[(rowOff + k*O + o)*ld + J[k,i]*P + p] = SG[k,i]*quant(W[i,o,p])
// scales[] holds SUMS; s = scales[i] * inv_n.
__global__ __launch_bounds__(256) void build_dense_kernel(
    const float* __restrict__ W, const float* __restrict__ scales, float inv_n,
    bf16* __restrict__ Wt, int O, int P, int ld, int rowOff, int total, OctTab tab) {
  int idx = blockIdx.x * 256 + threadIdx.x;
  if (idx >= total) return;
  int p = idx % P;
  int rest = idx / P;
  int o = rest % O;
  rest /= O;
  int i = rest & 7;
  int k = rest >> 3;
  float s = scales[i] * inv_n;
  float w = W[((size_t)i * O + o) * P + p];
  float q = rintf(w / (s + 1e-8f));
  q = fminf(1.f, fmaxf(-1.f, q)) * s;
  int j = tab.J[k * 8 + i];
  float sg = tab.SG[k * 8 + i];
  Wt[(size_t)(rowOff + k * O + o) * ld + j * P + p] = (bf16)(sg * q);
}

// zero K-pad columns 5464..5503 of Wd (2048 rows, ld 5504)
__global__ __launch_bounds__(256) void zero_pad_kernel(bf16* __restrict__ Wd) {
  int idx = blockIdx.x * 256 + threadIdx.x;  // 2048*40 = 81920
  if (idx >= 81920) return;
  int row = idx / 40, c = idx % 40;
  Wd[(size_t)row * 5504 + 5464 + c] = (bf16)0.f;
}

// ---------------------------------------------------------------- rmsnorm (f32 in -> bf16 out)
__global__ __launch_bounds__(256) void rmsnorm_kernel(
    const float* __restrict__ x, const float* __restrict__ w, bf16* __restrict__ out) {
  int row = blockIdx.x;
  int tid = threadIdx.x;
  const float4* xp = (const float4*)(x + (size_t)row * 2048);
  float4 a = xp[tid * 2], b = xp[tid * 2 + 1];
  float ss = a.x*a.x + a.y*a.y + a.z*a.z + a.w*a.w
           + b.x*b.x + b.y*b.y + b.z*b.z + b.w*b.w;
#pragma unroll
  for (int off = 32; off >= 1; off >>= 1) ss += __shfl_xor(ss, off);
  __shared__ float red[4];
  int lane = tid & 63, wvi = tid >> 6;
  if (lane == 0) red[wvi] = ss;
  __syncthreads();
  float tot = red[0] + red[1] + red[2] + red[3];
  float rms = rsqrtf(tot * (1.f / 2048.f) + 1e-6f);
  const float4* wp = (const float4*)w;
  float4 wa = wp[tid * 2], wb = wp[tid * 2 + 1];
  bf16x8 ov;
  ov[0] = (bf16)(a.x * rms * wa.x); ov[1] = (bf16)(a.y * rms * wa.y);
  ov[2] = (bf16)(a.z * rms * wa.z); ov[3] = (bf16)(a.w * rms * wa.w);
  ov[4] = (bf16)(b.x * rms * wb.x); ov[5] = (bf16)(b.y * rms * wb.y);
  ov[6] = (bf16)(b.z * rms * wb.z); ov[7] = (bf16)(b.w * rms * wb.w);
  *(bf16x8*)(out + (size_t)row * 2048 + tid * 8) = ov;
}

// ---------------------------------------------------------------- GEMM  C = A(MxK) * Bt(NxK)^T
// BM x 256 tile, 8 waves (2M x 4N), BK=64, 16x16x32 bf16 MFMA, depth-2 LDS double-buffer.
// Burst-STAGE tile kt+1 at iteration top, counted s_waitcnt vmcnt(TC), raw s_barrier.
// SCHED 0 (PHASED, R7-proven): 4 phases of {ds_read | barrier | setprio MFMA | barrier}.
// SCHED 1 (NOBAR, A/B probe): same reads/MFMA, NO inner barriers -> waves free-run within the
//   K-tile (ds_read of one wave overlaps MFMA of another); single end-of-tile barrier guards
//   the buffer against next iteration's STAGE overwrite. Reads only touch the stable buffer.
// Both-sides XOR swizzle (T2), bijective XCD swizzle (T1). Store guarded by col<Nst.
// MODE 0: bf16 store.  MODE 1: f32 store + f32 residual add.
// SIGNATURE: (A, Bt, res, Cout, K, Nst, ldC)
template <int BM, int MODE, int SCHED>
__global__ __launch_bounds__(512, 2) void gemm_tile(
    const bf16* __restrict__ A, const bf16* __restrict__ Bt,
    const float* __restrict__ res, void* __restrict__ Cout,
    int K, int Nst, int ldC) {
  constexpr int ABYTES = BM * 128;            // one A buffer (BM rows x 64 bf16)
  constexpr int ACH = BM / 64;                // A chunks per wave (1KB each)
  constexpr int TC  = ACH + 4;                // loads issued per tile per wave
  constexpr int MF  = BM / 32;                // per-wave M fragments
  constexpr int MFP = MF / 4;                 // M fragments per phase
  __shared__ char smem[2 * ABYTES + 65536];   // [A0][A1][B0][B1]
  const int tid = threadIdx.x;
  const int lane = tid & 63, wave = tid >> 6;
  int nwg = gridDim.x * gridDim.y;
  int lin = blockIdx.y * gridDim.x + blockIdx.x;
  if ((nwg & 7) == 0) lin = (lin & 7) * (nwg >> 3) + (lin >> 3);
  const int bm = (lin / gridDim.x) * BM;
  const int bn = (lin % gridDim.x) * 256;
  const int wm = wave >> 2, wn = wave & 3;    // 2 x 4 wave grid
  const int r = lane & 15, g = lane >> 4;
  const int srow = lane >> 3, sslot = lane & 7;

  f32x4 acc[MF][4] = {};
  const int nkt = K >> 6;

  auto STAGE = [&](int kt, int buf) {
    int k0 = kt << 6;
#pragma unroll
    for (int c = 0; c < ACH; ++c) {
      int ca = wave * ACH + c;
      int row = ca * 8 + srow;
      int sc = ((sslot ^ (row & 7)) << 3);    // pre-swizzled global source col (bf16 elems)
      gload_lds16(A + (size_t)(bm + row) * K + k0 + sc,
                  smem + buf * ABYTES + ca * 1024);
    }
#pragma unroll
    for (int c = 0; c < 4; ++c) {
      int cb = wave * 4 + c;
      int row = cb * 8 + srow;
      int sc = ((sslot ^ (row & 7)) << 3);
      gload_lds16(Bt + (size_t)(bn + row) * K + k0 + sc,
                  smem + 2 * ABYTES + buf * 32768 + cb * 1024);
    }
  };

  STAGE(0, 0);
  int cur = 0;
  for (int kt = 0; kt < nkt; ++kt) {
    if (kt + 1 < nkt) {
      STAGE(kt + 1, cur ^ 1);
      if constexpr (TC == 8) asm volatile("s_waitcnt vmcnt(8)" ::: "memory");
      else                   asm volatile("s_waitcnt vmcnt(6)" ::: "memory");
    } else {
      asm volatile("s_waitcnt vmcnt(0)" ::: "memory");
    }
    __builtin_amdgcn_s_barrier();
    const char* ab = smem + cur * ABYTES;
    const char* bb = smem + 2 * ABYTES + cur * 32768;
    bf16x8 bfr[4][2];
#pragma unroll
    for (int p = 0; p < 4; ++p) {
      if (p == 0) {
#pragma unroll
        for (int n = 0; n < 4; ++n)
#pragma unroll
          for (int kk = 0; kk < 2; ++kk) {
            int rown = wn * 64 + n * 16 + r;
            int cc = (kk * 4 + g) ^ (rown & 7);
            bfr[n][kk] = *(const bf16x8*)(bb + rown * 128 + cc * 16);
          }
      }
      bf16x8 af[MFP][2];
#pragma unroll
      for (int q = 0; q < MFP; ++q)
#pragma unroll
        for (int kk = 0; kk < 2; ++kk) {
          int rowm = wm * (BM / 2) + (p * MFP + q) * 16 + r;
          int cc = (kk * 4 + g) ^ (rowm & 7);
          af[q][kk] = *(const bf16x8*)(ab + rowm * 128 + cc * 16);
        }
      if constexpr (SCHED == 0) __builtin_amdgcn_s_barrier();  // phase fence
      __builtin_amdgcn_s_setprio(1);
#pragma unroll
      for (int q = 0; q < MFP; ++q)
#pragma unroll
        for (int n = 0; n < 4; ++n)
#pragma unroll
          for (int kk = 0; kk < 2; ++kk)
            acc[p * MFP + q][n] = __builtin_amdgcn_mfma_f32_16x16x32_bf16(
                af[q][kk], bfr[n][kk], acc[p * MFP + q][n], 0, 0, 0);
      __builtin_amdgcn_s_setprio(0);
      if constexpr (SCHED == 0) __builtin_amdgcn_s_barrier();  // phase close
    }
    if constexpr (SCHED == 1) __builtin_amdgcn_s_barrier();    // end-of-tile: all reads done
    cur ^= 1;
  }
#pragma unroll
  for (int mf = 0; mf < MF; ++mf) {
    int row0 = bm + wm * (BM / 2) + mf * 16 + g * 4;
#pragma unroll
    for (int nf = 0; nf < 4; ++nf) {
      int col = bn + wn * 64 + nf * 16 + r;
      if (col < Nst) {
#pragma unroll
        for (int j = 0; j < 4; ++j) {
          size_t off = (size_t)(row0 + j) * ldC + col;
          if (MODE == 0) ((bf16*)Cout)[off] = (bf16)acc[mf][nf][j];
          else           ((float*)Cout)[off] = acc[mf][nf][j] + res[off];
        }
      }
    }
  }
}

// ---------------------------------------------------------------- RoPE in-place on q,k halves of qkv
__global__ __launch_bounds__(256) void rope_kernel(
    bf16* __restrict__ qkv, const float* __restrict__ fc, const float* __restrict__ fs) {
  int tid = blockIdx.x * 256 + threadIdx.x;
  int ub = tid & 15;
  int h = (tid >> 4) & 15;
  int qk = (tid >> 8) & 1;
  int row = tid >> 9;
  int t = row & 1023;
  bf16* p = qkv + (size_t)row * 6144 + qk * 2048 + h * 128 + ub * 8;
  bf16x8 v = *(bf16x8*)p;
  const float4 cv = *(const float4*)(fc + t * 64 + ub * 4);
  const float4 sv = *(const float4*)(fs + t * 64 + ub * 4);
  float cr[4] = {cv.x, cv.y, cv.z, cv.w};
  float sr[4] = {sv.x, sv.y, sv.z, sv.w};
  bf16x8 ov;
#pragma unroll
  for (int u = 0; u < 4; ++u) {
    float xr = (float)v[2 * u], xi = (float)v[2 * u + 1];
    ov[2 * u]     = (bf16)(xr * cr[u] - xi * sr[u]);
    ov[2 * u + 1] = (bf16)(xr * sr[u] + xi * cr[u]);
  }
  *(bf16x8*)p = ov;
}

// ---------------------------------------------------------------- flash attention (causal)
// grid (64 bh, 16 qtiles), 256 thr. Wave = 16 q-rows; kv chunks of 32.
// Vt unit-level XOR swizzle (write 16-way conflict fix, round-3 verified).
__global__ __launch_bounds__(256) void attn_kernel(
    const bf16* __restrict__ qkv, bf16* __restrict__ y) {
  __shared__ bf16 Vt[128][40];
  __shared__ bf16 P[4][16][40];
  int tid = threadIdx.x;
  int lane = tid & 63, wvi = tid >> 6;
  int bh = blockIdx.x, qt = blockIdx.y;
  int b = bh >> 4, h = bh & 15;
  int q0 = qt * 64;
  int r = lane & 15, g = lane >> 4;
  const bf16* base = qkv + (size_t)b * 1024 * 6144;
  bf16x8 qf[4];
  {
    const bf16* qp = base + (size_t)(q0 + wvi * 16 + r) * 6144 + h * 128 + g * 8;
#pragma unroll
    for (int kk = 0; kk < 4; ++kk) qf[kk] = *(const bf16x8*)(qp + kk * 32);
  }
  f32x4 o[8];
#pragma unroll
  for (int d = 0; d < 8; ++d) o[d] = (f32x4){0.f, 0.f, 0.f, 0.f};
  float m_run[4], l_run[4];
#pragma unroll
  for (int j = 0; j < 4; ++j) { m_run[j] = -1e30f; l_run[j] = 0.f; }
  const float sc = 0.08838834764831845f; // 1/sqrt(128)
  int nch = (q0 >> 5) + 2;
  for (int c = 0; c < nch; ++c) {
    __syncthreads();
#pragma unroll
    for (int it = 0; it < 2; ++it) {  // stage V chunk transposed (swizzled units)
      int e = it * 256 + tid;
      int vr = e >> 4, dg = e & 15;
      bf16x8 vvv = *(const bf16x8*)(base + (size_t)(c * 32 + vr) * 6144 + 4096 + h * 128 + dg * 8);
      int ub = vr >> 3, uo = vr & 7;
#pragma unroll
      for (int u = 0; u < 8; ++u) {
        int R = dg * 8 + u;
        Vt[R][((ub ^ ((R >> 3) & 3)) << 3) + uo] = vvv[u];
      }
    }
    __syncthreads();
    f32x4 s0 = {0, 0, 0, 0}, s1 = {0, 0, 0, 0};
    const bf16* kp = base + (size_t)(c * 32 + r) * 6144 + 2048 + h * 128 + g * 8;
#pragma unroll
    for (int kk = 0; kk < 4; ++kk) {
      bf16x8 kf0 = *(const bf16x8*)(kp + kk * 32);
      bf16x8 kf1 = *(const bf16x8*)(kp + (size_t)16 * 6144 + kk * 32);
      s0 = __builtin_amdgcn_mfma_f32_16x16x32_bf16(qf[kk], kf0, s0, 0, 0, 0);
      s1 = __builtin_amdgcn_mfma_f32_16x16x32_bf16(qf[kk], kf1, s1, 0, 0, 0);
    }
    int qrow = q0 + wvi * 16 + g * 4;
    int kc = c * 32 + r;
    float pmax[4];
#pragma unroll
    for (int j = 0; j < 4; ++j) {
      float a0 = s0[j] * sc, a1 = s1[j] * sc;
      if (kc > qrow + j) a0 = -1e30f;
      if (kc + 16 > qrow + j) a1 = -1e30f;
      s0[j] = a0; s1[j] = a1;
      pmax[j] = fmaxf(a0, a1);
    }
#pragma unroll
    for (int j = 0; j < 4; ++j) {
#pragma unroll
      for (int w = 8; w >= 1; w >>= 1) pmax[j] = fmaxf(pmax[j], __shfl_xor(pmax[j], w));
    }
    float corr[4], rsum[4];
#pragma unroll
    for (int j = 0; j < 4; ++j) {
      float nm = fmaxf(m_run[j], pmax[j]);
      corr[j] = __expf(m_run[j] - nm);
      m_run[j] = nm;
      float p0 = __expf(s0[j] - nm), p1 = __expf(s1[j] - nm);
      s0[j] = p0; s1[j] = p1;
      rsum[j] = p0 + p1;
    }
#pragma unroll
    for (int j = 0; j < 4; ++j) {
#pragma unroll
      for (int w = 8; w >= 1; w >>= 1) rsum[j] += __shfl_xor(rsum[j], w);
      l_run[j] = l_run[j] * corr[j] + rsum[j];
      P[wvi][g * 4 + j][r] = (bf16)s0[j];
      P[wvi][g * 4 + j][16 + r] = (bf16)s1[j];
    }
#pragma unroll
    for (int d = 0; d < 8; ++d)
#pragma unroll
      for (int j = 0; j < 4; ++j) o[d][j] *= corr[j];
    asm volatile("s_waitcnt lgkmcnt(0)" ::: "memory");
    bf16x8 pa = *(const bf16x8*)&P[wvi][r][g * 8];
#pragma unroll
    for (int d = 0; d < 8; ++d) {
      int R = d * 16 + r;
      bf16x8 vb = *(const bf16x8*)&Vt[R][(g ^ ((R >> 3) & 3)) << 3];
      o[d] = __builtin_amdgcn_mfma_f32_16x16x32_bf16(pa, vb, o[d], 0, 0, 0);
    }
  }
#pragma unroll
  for (int j = 0; j < 4; ++j) {
    float inv = 1.f / l_run[j];
    size_t row = (size_t)(b * 1024 + q0 + wvi * 16 + g * 4 + j);
    bf16* yp = y + row * 2048 + h * 128 + r;
#pragma unroll
    for (int d = 0; d < 8; ++d) yp[d * 16] = (bf16)(o[d][j] * inv);
  }
}

// ---------------------------------------------------------------- silu(gate)*up -> act (in-place over gate)
__global__ __launch_bounds__(256) void silu_kernel(
    const bf16* __restrict__ up, bf16* __restrict__ gate_act) {
  int tid = blockIdx.x * 256 + threadIdx.x;
  int jb = tid % 688;
  int row = tid / 688;
  size_t off = (size_t)row * 5504 + jb * 8;
  bf16x8 ov;
  if (jb < 683) {
    bf16x8 gv = *(const bf16x8*)(gate_act + off);
    bf16x8 uv = *(const bf16x8*)(up + off);
#pragma unroll
    for (int u = 0; u < 8; ++u) {
      float gg = (float)gv[u], uu = (float)uv[u];
      ov[u] = (bf16)(gg / (1.f + __expf(-gg)) * uu);
    }
  } else {
#pragma unroll
    for (int u = 0; u < 8; ++u) ov[u] = (bf16)0.f;  // zero K-pad cols 5464..5503
  }
  *(bf16x8*)(gate_act + off) = ov;
}

// ---------------------------------------------------------------- host
static void build_oct(OctTab& t) {
  int idx[8][8]; float sgn[8][8];
  for (int j = 0; j < 8; ++j) { idx[0][j] = j; sgn[0][j] = 1.f; }
  for (int i = 1; i < 8; ++i) {
    idx[i][0] = i; sgn[i][0] = 1.f;
    idx[i][i] = 0; sgn[i][i] = -1.f;
  }
  const int tr[7][3] = {{1,2,3},{1,4,5},{1,7,6},{2,4,6},{2,5,7},{3,4,7},{3,6,5}};
  for (int ti = 0; ti < 7; ++ti) {
    int a = tr[ti][0], b = tr[ti][1], c = tr[ti][2];
    int cyc[3][3] = {{a,b,c},{b,c,a},{c,a,b}};
    for (int ci = 0; ci < 3; ++ci) {
      int p = cyc[ci][0], q = cyc[ci][1], r = cyc[ci][2];
      idx[p][q] = r; sgn[p][q] = 1.f;
      idx[q][p] = r; sgn[q][p] = -1.f;
    }
  }
  for (int i = 0; i < 8; ++i)
    for (int j = 0; j < 8; ++j) {
      int k = idx[i][j];
      t.J[k * 8 + i] = j;
      t.SG[k * 8 + i] = sgn[i][j];
    }
}

// workspace layout (bytes), aliased:
#define OFF_SCALES 0ull
#define OFF_WBUF   256ull
#define OFF_R16    (OFF_WBUF + 25165824ull)   // max weight = Wqkv 6144x2048 bf16
#define OFF_QKVR   (OFF_R16 + 16777216ull)
#define OFF_H      (OFF_QKVR + 50331648ull)
#define OFF_G1     (OFF_H + 33554432ull)
#define WS_NEED    (OFF_G1 + 45088768ull)     // ~163 MB

extern "C" void kernel_launch(void* const* d_in, const int* in_sizes, int n_in,
                              void* d_out, int out_size, void* d_ws, size_t ws_size,
                              hipStream_t stream) {
  (void)in_sizes; (void)n_in; (void)out_size;
  if (ws_size < WS_NEED) return;

  const float* x   = (const float*)d_in[0];
  const float* fc  = (const float*)d_in[1];
  const float* fs  = (const float*)d_in[2];
  const float* anw = (const float*)d_in[3];
  const float* fnw = (const float*)d_in[4];
  const float* wqw = (const float*)d_in[5];
  const float* wkw = (const float*)d_in[6];
  const float* wvw = (const float*)d_in[7];
  const float* wow = (const float*)d_in[8];
  const float* wgw = (const float*)d_in[9];
  const float* wuw = (const float*)d_in[10];
  const float* wdw = (const float*)d_in[11];

  char* ws = (char*)d_ws;
  float* scales = (float*)(ws + OFF_SCALES);
  bf16* Wbuf = (bf16*)(ws + OFF_WBUF);
  bf16* xn   = (bf16*)(ws + OFF_R16);   // then y, then hn
  bf16* qkv  = (bf16*)(ws + OFF_QKVR);  // then up
  float* h   = (float*)(ws + OFF_H);
  bf16* g1   = (bf16*)(ws + OFF_G1);    // gate, then act in-place

  OctTab tab; build_oct(tab);
  Ptr7 p7;
  p7.p[0] = wqw; p7.p[1] = wkw; p7.p[2] = wvw; p7.p[3] = wow;
  p7.p[4] = wgw; p7.p[5] = wuw; p7.p[6] = wdw;
  for (int i = 0; i < 4; ++i) p7.opsz[i] = 65536;
  for (int i = 4; i < 7; ++i) p7.opsz[i] = 174848;

  const float invS = 1.f / 65536.f;   // small tensors (q,k,v,o)
  const float invL = 1.f / 174848.f;  // large tensors (gate,up,down)

  scales_zero<<<1, 64, 0, stream>>>(scales);
  scales_partial<<<448, 256, 0, stream>>>(p7, scales);

  // ---- QKV: build fused [Wq;Wk;Wv] (6144x2048), gemm, rope, attention
  build_dense_kernel<<<16384, 256, 0, stream>>>(wqw, scales + 0,  invS, Wbuf, 256, 256, 2048, 0,    4194304, tab);
  build_dense_kernel<<<16384, 256, 0, stream>>>(wkw, scales + 8,  invS, Wbuf, 256, 256, 2048, 2048, 4194304, tab);
  build_dense_kernel<<<16384, 256, 0, stream>>>(wvw, scales + 16, invS, Wbuf, 256, 256, 2048, 4096, 4194304, tab);
  rmsnorm_kernel<<<4096, 256, 0, stream>>>(x, anw, xn);
  // 128x256 tile -> grid 24x32 = 768 blocks = 3.0 tail-free rounds
  gemm_tile<128, 0, 0><<<dim3(24, 32), 512, 0, stream>>>(xn, Wbuf, nullptr, qkv, 2048, 6144, 6144);
  rope_kernel<<<8192, 256, 0, stream>>>(qkv, fc, fs);
  attn_kernel<<<dim3(64, 16), 256, 0, stream>>>(qkv, (bf16*)(ws + OFF_R16) /* y over xn */);

  // ---- O-proj + residual (f32): 128x256 tile, grid 8x32 = 256 blocks (tail-free). K=2048.
  build_dense_kernel<<<16384, 256, 0, stream>>>(wow, scales + 24, invS, Wbuf, 256, 256, 2048, 0, 4194304, tab);
  gemm_tile<128, 1, 0><<<dim3(8, 32), 512, 0, stream>>>((bf16*)(ws + OFF_R16), Wbuf, x, h, 2048, 2048, 2048);

  // ---- FFN
  bf16* hn = (bf16*)(ws + OFF_R16);  // overwrite y (dead)
  rmsnorm_kernel<<<4096, 256, 0, stream>>>(h, fnw, hn);
  // *** A/B experiment: gate uses SCHED=1 (NOBAR free-run), up uses SCHED=0 (PHASED, proven).
  // *** Identical shape/grid/A-operand -> within-probe schedule comparison in the profile.
  build_dense_kernel<<<43712, 256, 0, stream>>>(wgw, scales + 32, invL, Wbuf, 683, 256, 2048, 0, 11190272, tab);
  gemm_tile<128, 0, 1><<<dim3(22, 32), 512, 0, stream>>>(hn, Wbuf, nullptr, g1, 2048, 5504, 5504);
  // up: rebuild Wbuf, gemm -> qkv region (dead)
  bf16* up = (bf16*)(ws + OFF_QKVR);
  build_dense_kernel<<<43712, 256, 0, stream>>>(wuw, scales + 40, invL, Wbuf, 683, 256, 2048, 0, 11190272, tab);
  gemm_tile<128, 0, 0><<<dim3(22, 32), 512, 0, stream>>>(hn, Wbuf, nullptr, up, 2048, 5504, 5504);
  // silu(gate)*up -> act (in-place over gate), zeroing K-pad cols
  silu_kernel<<<11008, 256, 0, stream>>>(up, g1);
  // down: build Wd (2048x5504, zero the 40 pad cols), 128x256 tile K=5504 + residual -> out
  build_dense_kernel<<<43712, 256, 0, stream>>>(wdw, scales + 48, invL, Wbuf, 256, 683, 5504, 0, 11190272, tab);
  zero_pad_kernel<<<320, 256, 0, stream>>>(Wbuf);
  gemm_tile<128, 1, 0><<<dim3(8, 32), 512, 0, stream>>>(g1, Wbuf, h, (float*)d_out, 5504, 2048, 2048);
}

// Round 11
// 913.132 us; speedup vs baseline: 1.0861x; 1.0095x over previous
//
#include <hip/hip_runtime.h>
#include <stdint.h>

typedef __bf16 bf16;
typedef __bf16 bf16x8 __attribute__((ext_vector_type(8)));
typedef float f32x4 __attribute__((ext_vector_type(4)));

typedef const uint32_t __attribute__((address_space(1))) guint_t;
typedef uint32_t __attribute__((address_space(3))) luint_t;

__device__ __forceinline__ void gload_lds16(const void* g, void* l) {
  __builtin_amdgcn_global_load_lds((guint_t*)g, (luint_t*)l, 16, 0, 0);
}

// ---------------------------------------------------------------- weight prep
struct OctTab { int J[64]; float SG[64]; };
struct Ptr7 { const float* p[7]; int opsz[7]; };

__global__ void scales_zero(float* __restrict__ scales) {
  if (threadIdx.x < 56) scales[threadIdx.x] = 0.f;
}

// 448 blocks: 8 partials per (tensor,i) slice, atomicAdd of sum|W| (mean applied in build via inv_n)
__global__ __launch_bounds__(256) void scales_partial(Ptr7 t, float* __restrict__ scales) {
  int bx = blockIdx.x;
  int part = bx & 7, sl = bx >> 3;
  int ti = sl >> 3, i = sl & 7;
  int n = t.opsz[ti];
  int n4 = n >> 2, seg = n4 >> 3;
  const float4* base = (const float4*)(t.p[ti] + (size_t)i * n) + part * seg;
  float s = 0.f;
  for (int j = threadIdx.x; j < seg; j += 256) {
    float4 v = base[j];
    s += fabsf(v.x) + fabsf(v.y) + fabsf(v.z) + fabsf(v.w);
  }
#pragma unroll
  for (int off = 32; off >= 1; off >>= 1) s += __shfl_xor(s, off);
  __shared__ float red[4];
  int lane = threadIdx.x & 63, wvi = threadIdx.x >> 6;
  if (lane == 0) red[wvi] = s;
  __syncthreads();
  if (threadIdx.x == 0) atomicAdd(&scales[sl], red[0] + red[1] + red[2] + red[3]);
}

// Dense expansion: Wt[(rowOff + k*O + o)*ld + J[k,i]*P + p] = SG[k,i]*quant(W[i,o,p])
// scales[] holds SUMS; s = scales[i] * inv_n.
__global__ __launch_bounds__(256) void build_dense_kernel(
    const float* __restrict__ W, const float* __restrict__ scales, float inv_n,
    bf16* __restrict__ Wt, int O, int P, int ld, int rowOff, int total, OctTab tab) {
  int idx = blockIdx.x * 256 + threadIdx.x;
  if (idx >= total) return;
  int p = idx % P;
  int rest = idx / P;
  int o = rest % O;
  rest /= O;
  int i = rest & 7;
  int k = rest >> 3;
  float s = scales[i] * inv_n;
  float w = W[((size_t)i * O + o) * P + p];
  float q = rintf(w / (s + 1e-8f));
  q = fminf(1.f, fmaxf(-1.f, q)) * s;
  int j = tab.J[k * 8 + i];
  float sg = tab.SG[k * 8 + i];
  Wt[(size_t)(rowOff + k * O + o) * ld + j * P + p] = (bf16)(sg * q);
}

// zero K-pad columns 5464..5503 of Wd (2048 rows, ld 5504)
__global__ __launch_bounds__(256) void zero_pad_kernel(bf16* __restrict__ Wd) {
  int idx = blockIdx.x * 256 + threadIdx.x;  // 2048*40 = 81920
  if (idx >= 81920) return;
  int row = idx / 40, c = idx % 40;
  Wd[(size_t)row * 5504 + 5464 + c] = (bf16)0.f;
}

// ---------------------------------------------------------------- rmsnorm (f32 in -> bf16 out)
__global__ __launch_bounds__(256) void rmsnorm_kernel(
    const float* __restrict__ x, const float* __restrict__ w, bf16* __restrict__ out) {
  int row = blockIdx.x;
  int tid = threadIdx.x;
  const float4* xp = (const float4*)(x + (size_t)row * 2048);
  float4 a = xp[tid * 2], b = xp[tid * 2 + 1];
  float ss = a.x*a.x + a.y*a.y + a.z*a.z + a.w*a.w
           + b.x*b.x + b.y*b.y + b.z*b.z + b.w*b.w;
#pragma unroll
  for (int off = 32; off >= 1; off >>= 1) ss += __shfl_xor(ss, off);
  __shared__ float red[4];
  int lane = tid & 63, wvi = tid >> 6;
  if (lane == 0) red[wvi] = ss;
  __syncthreads();
  float tot = red[0] + red[1] + red[2] + red[3];
  float rms = rsqrtf(tot * (1.f / 2048.f) + 1e-6f);
  const float4* wp = (const float4*)w;
  float4 wa = wp[tid * 2], wb = wp[tid * 2 + 1];
  bf16x8 ov;
  ov[0] = (bf16)(a.x * rms * wa.x); ov[1] = (bf16)(a.y * rms * wa.y);
  ov[2] = (bf16)(a.z * rms * wa.z); ov[3] = (bf16)(a.w * rms * wa.w);
  ov[4] = (bf16)(b.x * rms * wb.x); ov[5] = (bf16)(b.y * rms * wb.y);
  ov[6] = (bf16)(b.z * rms * wb.z); ov[7] = (bf16)(b.w * rms * wb.w);
  *(bf16x8*)(out + (size_t)row * 2048 + tid * 8) = ov;
}

// ---------------------------------------------------------------- GEMM  C = A(MxK) * Bt(NxK)^T
// BM x 256 tile, 8 waves (2M x 4N), BK=64, 16x16x32 bf16 MFMA.
// SCHED 0 (PHASED depth-2, R7-proven): burst-STAGE kt+1, vmcnt(TC), 4 phases with 2 barriers each.
// SCHED 1 (NOBAR depth-2): same, no inner barriers (R9: == SCHED 0 within noise).
// SCHED 2 (DEPTH-3 probe): triple-buffered LDS; stage kt+2 at iter top; counted vmcnt(2*TC)
//   keeps 12 future loads in flight across barriers; 2 barriers/K-tile.
// Both-sides XOR swizzle (T2), bijective XCD swizzle (T1). Store guarded by col<Nst.
// MODE 0: bf16 store.  MODE 1: f32 store + f32 residual add.
// SIGNATURE: (A, Bt, res, Cout, K, Nst, ldC)
template <int BM, int MODE, int SCHED>
__global__ __launch_bounds__(512, 2) void gemm_tile(
    const bf16* __restrict__ A, const bf16* __restrict__ Bt,
    const float* __restrict__ res, void* __restrict__ Cout,
    int K, int Nst, int ldC) {
  constexpr int ABYTES = BM * 128;            // one A buffer (BM rows x 64 bf16)
  constexpr int ACH = BM / 64;                // A chunks per wave (1KB each)
  constexpr int TC  = ACH + 4;                // loads issued per tile per wave
  constexpr int MF  = BM / 32;                // per-wave M fragments
  constexpr int MFP = MF / 4;                 // M fragments per phase
  constexpr int NBUF = (SCHED == 2) ? 3 : 2;
  __shared__ char smem[NBUF * (ABYTES + 32768)];
  char* const Abase = smem;
  char* const Bbase = smem + NBUF * ABYTES;
  const int tid = threadIdx.x;
  const int lane = tid & 63, wave = tid >> 6;
  int nwg = gridDim.x * gridDim.y;
  int lin = blockIdx.y * gridDim.x + blockIdx.x;
  if ((nwg & 7) == 0) lin = (lin & 7) * (nwg >> 3) + (lin >> 3);
  const int bm = (lin / gridDim.x) * BM;
  const int bn = (lin % gridDim.x) * 256;
  const int wm = wave >> 2, wn = wave & 3;    // 2 x 4 wave grid
  const int r = lane & 15, g = lane >> 4;
  const int srow = lane >> 3, sslot = lane & 7;

  f32x4 acc[MF][4] = {};
  const int nkt = K >> 6;

  auto STAGE = [&](int kt, int buf) {
    int k0 = kt << 6;
#pragma unroll
    for (int c = 0; c < ACH; ++c) {
      int ca = wave * ACH + c;
      int row = ca * 8 + srow;
      int sc = ((sslot ^ (row & 7)) << 3);    // pre-swizzled global source col (bf16 elems)
      gload_lds16(A + (size_t)(bm + row) * K + k0 + sc,
                  Abase + buf * ABYTES + ca * 1024);
    }
#pragma unroll
    for (int c = 0; c < 4; ++c) {
      int cb = wave * 4 + c;
      int row = cb * 8 + srow;
      int sc = ((sslot ^ (row & 7)) << 3);
      gload_lds16(Bt + (size_t)(bn + row) * K + k0 + sc,
                  Bbase + buf * 32768 + cb * 1024);
    }
  };

  auto COMPUTE = [&](const char* ab, const char* bb) {
    bf16x8 bfr[4][2];
#pragma unroll
    for (int p = 0; p < 4; ++p) {
      if (p == 0) {
#pragma unroll
        for (int n = 0; n < 4; ++n)
#pragma unroll
          for (int kk = 0; kk < 2; ++kk) {
            int rown = wn * 64 + n * 16 + r;
            int cc = (kk * 4 + g) ^ (rown & 7);
            bfr[n][kk] = *(const bf16x8*)(bb + rown * 128 + cc * 16);
          }
      }
      bf16x8 af[MFP][2];
#pragma unroll
      for (int q = 0; q < MFP; ++q)
#pragma unroll
        for (int kk = 0; kk < 2; ++kk) {
          int rowm = wm * (BM / 2) + (p * MFP + q) * 16 + r;
          int cc = (kk * 4 + g) ^ (rowm & 7);
          af[q][kk] = *(const bf16x8*)(ab + rowm * 128 + cc * 16);
        }
      if constexpr (SCHED == 0) __builtin_amdgcn_s_barrier();
      __builtin_amdgcn_s_setprio(1);
#pragma unroll
      for (int q = 0; q < MFP; ++q)
#pragma unroll
        for (int n = 0; n < 4; ++n)
#pragma unroll
          for (int kk = 0; kk < 2; ++kk)
            acc[p * MFP + q][n] = __builtin_amdgcn_mfma_f32_16x16x32_bf16(
                af[q][kk], bfr[n][kk], acc[p * MFP + q][n], 0, 0, 0);
      __builtin_amdgcn_s_setprio(0);
      if constexpr (SCHED == 0) __builtin_amdgcn_s_barrier();
    }
  };

  if constexpr (SCHED == 2) {
    STAGE(0, 0);
    if (nkt > 1) STAGE(1, 1);
    int b = 0;
    for (int kt = 0; kt < nkt; ++kt) {
      if (kt + 2 < nkt) STAGE(kt + 2, (b + 2 >= 3) ? b - 1 : b + 2);
      int rem = nkt - 1 - kt;
      if (rem >= 2) {
        if constexpr (TC == 6) asm volatile("s_waitcnt vmcnt(12)" ::: "memory");
        else                   asm volatile("s_waitcnt vmcnt(16)" ::: "memory");
      } else if (rem == 1) {
        if constexpr (TC == 6) asm volatile("s_waitcnt vmcnt(6)" ::: "memory");
        else                   asm volatile("s_waitcnt vmcnt(8)" ::: "memory");
      } else {
        asm volatile("s_waitcnt vmcnt(0)" ::: "memory");
      }
      __builtin_amdgcn_s_barrier();      // staged writes of tile kt visible block-wide
      COMPUTE(Abase + b * ABYTES, Bbase + b * 32768);
      __builtin_amdgcn_s_barrier();      // all reads of buf b done before its next overwrite
      b = (b + 1 == 3) ? 0 : b + 1;
    }
  } else {
    STAGE(0, 0);
    int cur = 0;
    for (int kt = 0; kt < nkt; ++kt) {
      if (kt + 1 < nkt) {
        STAGE(kt + 1, cur ^ 1);
        if constexpr (TC == 8) asm volatile("s_waitcnt vmcnt(8)" ::: "memory");
        else                   asm volatile("s_waitcnt vmcnt(6)" ::: "memory");
      } else {
        asm volatile("s_waitcnt vmcnt(0)" ::: "memory");
      }
      __builtin_amdgcn_s_barrier();
      COMPUTE(Abase + cur * ABYTES, Bbase + cur * 32768);
      if constexpr (SCHED == 1) __builtin_amdgcn_s_barrier();
      cur ^= 1;
    }
  }

#pragma unroll
  for (int mf = 0; mf < MF; ++mf) {
    int row0 = bm + wm * (BM / 2) + mf * 16 + g * 4;
#pragma unroll
    for (int nf = 0; nf < 4; ++nf) {
      int col = bn + wn * 64 + nf * 16 + r;
      if (col < Nst) {
#pragma unroll
        for (int j = 0; j < 4; ++j) {
          size_t off = (size_t)(row0 + j) * ldC + col;
          if (MODE == 0) ((bf16*)Cout)[off] = (bf16)acc[mf][nf][j];
          else           ((float*)Cout)[off] = acc[mf][nf][j] + res[off];
        }
      }
    }
  }
}

// ---------------------------------------------------------------- RoPE in-place on q,k halves of qkv
__global__ __launch_bounds__(256) void rope_kernel(
    bf16* __restrict__ qkv, const float* __restrict__ fc, const float* __restrict__ fs) {
  int tid = blockIdx.x * 256 + threadIdx.x;
  int ub = tid & 15;
  int h = (tid >> 4) & 15;
  int qk = (tid >> 8) & 1;
  int row = tid >> 9;
  int t = row & 1023;
  bf16* p = qkv + (size_t)row * 6144 + qk * 2048 + h * 128 + ub * 8;
  bf16x8 v = *(bf16x8*)p;
  const float4 cv = *(const float4*)(fc + t * 64 + ub * 4);
  const float4 sv = *(const float4*)(fs + t * 64 + ub * 4);
  float cr[4] = {cv.x, cv.y, cv.z, cv.w};
  float sr[4] = {sv.x, sv.y, sv.z, sv.w};
  bf16x8 ov;
#pragma unroll
  for (int u = 0; u < 4; ++u) {
    float xr = (float)v[2 * u], xi = (float)v[2 * u + 1];
    ov[2 * u]     = (bf16)(xr * cr[u] - xi * sr[u]);
    ov[2 * u + 1] = (bf16)(xr * sr[u] + xi * cr[u]);
  }
  *(bf16x8*)p = ov;
}

// ---------------------------------------------------------------- flash attention (causal)
// grid (64 bh, 16 qtiles), 256 thr. Wave = 16 q-rows; kv chunks of 32.
// Vt unit-level XOR swizzle (write 16-way conflict fix, round-3 verified).
__global__ __launch_bounds__(256) void attn_kernel(
    const bf16* __restrict__ qkv, bf16* __restrict__ y) {
  __shared__ bf16 Vt[128][40];
  __shared__ bf16 P[4][16][40];
  int tid = threadIdx.x;
  int lane = tid & 63, wvi = tid >> 6;
  int bh = blockIdx.x, qt = blockIdx.y;
  int b = bh >> 4, h = bh & 15;
  int q0 = qt * 64;
  int r = lane & 15, g = lane >> 4;
  const bf16* base = qkv + (size_t)b * 1024 * 6144;
  bf16x8 qf[4];
  {
    const bf16* qp = base + (size_t)(q0 + wvi * 16 + r) * 6144 + h * 128 + g * 8;
#pragma unroll
    for (int kk = 0; kk < 4; ++kk) qf[kk] = *(const bf16x8*)(qp + kk * 32);
  }
  f32x4 o[8];
#pragma unroll
  for (int d = 0; d < 8; ++d) o[d] = (f32x4){0.f, 0.f, 0.f, 0.f};
  float m_run[4], l_run[4];
#pragma unroll
  for (int j = 0; j < 4; ++j) { m_run[j] = -1e30f; l_run[j] = 0.f; }
  const float sc = 0.08838834764831845f; // 1/sqrt(128)
  int nch = (q0 >> 5) + 2;
  for (int c = 0; c < nch; ++c) {
    __syncthreads();
#pragma unroll
    for (int it = 0; it < 2; ++it) {  // stage V chunk transposed (swizzled units)
      int e = it * 256 + tid;
      int vr = e >> 4, dg = e & 15;
      bf16x8 vvv = *(const bf16x8*)(base + (size_t)(c * 32 + vr) * 6144 + 4096 + h * 128 + dg * 8);
      int ub = vr >> 3, uo = vr & 7;
#pragma unroll
      for (int u = 0; u < 8; ++u) {
        int R = dg * 8 + u;
        Vt[R][((ub ^ ((R >> 3) & 3)) << 3) + uo] = vvv[u];
      }
    }
    __syncthreads();
    f32x4 s0 = {0, 0, 0, 0}, s1 = {0, 0, 0, 0};
    const bf16* kp = base + (size_t)(c * 32 + r) * 6144 + 2048 + h * 128 + g * 8;
#pragma unroll
    for (int kk = 0; kk < 4; ++kk) {
      bf16x8 kf0 = *(const bf16x8*)(kp + kk * 32);
      bf16x8 kf1 = *(const bf16x8*)(kp + (size_t)16 * 6144 + kk * 32);
      s0 = __builtin_amdgcn_mfma_f32_16x16x32_bf16(qf[kk], kf0, s0, 0, 0, 0);
      s1 = __builtin_amdgcn_mfma_f32_16x16x32_bf16(qf[kk], kf1, s1, 0, 0, 0);
    }
    int qrow = q0 + wvi * 16 + g * 4;
    int kc = c * 32 + r;
    float pmax[4];
#pragma unroll
    for (int j = 0; j < 4; ++j) {
      float a0 = s0[j] * sc, a1 = s1[j] * sc;
      if (kc > qrow + j) a0 = -1e30f;
      if (kc + 16 > qrow + j) a1 = -1e30f;
      s0[j] = a0; s1[j] = a1;
      pmax[j] = fmaxf(a0, a1);
    }
#pragma unroll
    for (int j = 0; j < 4; ++j) {
#pragma unroll
      for (int w = 8; w >= 1; w >>= 1) pmax[j] = fmaxf(pmax[j], __shfl_xor(pmax[j], w));
    }
    float corr[4], rsum[4];
#pragma unroll
    for (int j = 0; j < 4; ++j) {
      float nm = fmaxf(m_run[j], pmax[j]);
      corr[j] = __expf(m_run[j] - nm);
      m_run[j] = nm;
      float p0 = __expf(s0[j] - nm), p1 = __expf(s1[j] - nm);
      s0[j] = p0; s1[j] = p1;
      rsum[j] = p0 + p1;
    }
#pragma unroll
    for (int j = 0; j < 4; ++j) {
#pragma unroll
      for (int w = 8; w >= 1; w >>= 1) rsum[j] += __shfl_xor(rsum[j], w);
      l_run[j] = l_run[j] * corr[j] + rsum[j];
      P[wvi][g * 4 + j][r] = (bf16)s0[j];
      P[wvi][g * 4 + j][16 + r] = (bf16)s1[j];
    }
#pragma unroll
    for (int d = 0; d < 8; ++d)
#pragma unroll
      for (int j = 0; j < 4; ++j) o[d][j] *= corr[j];
    asm volatile("s_waitcnt lgkmcnt(0)" ::: "memory");
    bf16x8 pa = *(const bf16x8*)&P[wvi][r][g * 8];
#pragma unroll
    for (int d = 0; d < 8; ++d) {
      int R = d * 16 + r;
      bf16x8 vb = *(const bf16x8*)&Vt[R][(g ^ ((R >> 3) & 3)) << 3];
      o[d] = __builtin_amdgcn_mfma_f32_16x16x32_bf16(pa, vb, o[d], 0, 0, 0);
    }
  }
#pragma unroll
  for (int j = 0; j < 4; ++j) {
    float inv = 1.f / l_run[j];
    size_t row = (size_t)(b * 1024 + q0 + wvi * 16 + g * 4 + j);
    bf16* yp = y + row * 2048 + h * 128 + r;
#pragma unroll
    for (int d = 0; d < 8; ++d) yp[d * 16] = (bf16)(o[d][j] * inv);
  }
}

// ---------------------------------------------------------------- silu(gate)*up -> act (in-place over gate)
__global__ __launch_bounds__(256) void silu_kernel(
    const bf16* __restrict__ up, bf16* __restrict__ gate_act) {
  int tid = blockIdx.x * 256 + threadIdx.x;
  int jb = tid % 688;
  int row = tid / 688;
  size_t off = (size_t)row * 5504 + jb * 8;
  bf16x8 ov;
  if (jb < 683) {
    bf16x8 gv = *(const bf16x8*)(gate_act + off);
    bf16x8 uv = *(const bf16x8*)(up + off);
#pragma unroll
    for (int u = 0; u < 8; ++u) {
      float gg = (float)gv[u], uu = (float)uv[u];
      ov[u] = (bf16)(gg / (1.f + __expf(-gg)) * uu);
    }
  } else {
#pragma unroll
    for (int u = 0; u < 8; ++u) ov[u] = (bf16)0.f;  // zero K-pad cols 5464..5503
  }
  *(bf16x8*)(gate_act + off) = ov;
}

// ---------------------------------------------------------------- host
static void build_oct(OctTab& t) {
  int idx[8][8]; float sgn[8][8];
  for (int j = 0; j < 8; ++j) { idx[0][j] = j; sgn[0][j] = 1.f; }
  for (int i = 1; i < 8; ++i) {
    idx[i][0] = i; sgn[i][0] = 1.f;
    idx[i][i] = 0; sgn[i][i] = -1.f;
  }
  const int tr[7][3] = {{1,2,3},{1,4,5},{1,7,6},{2,4,6},{2,5,7},{3,4,7},{3,6,5}};
  for (int ti = 0; ti < 7; ++ti) {
    int a = tr[ti][0], b = tr[ti][1], c = tr[ti][2];
    int cyc[3][3] = {{a,b,c},{b,c,a},{c,a,b}};
    for (int ci = 0; ci < 3; ++ci) {
      int p = cyc[ci][0], q = cyc[ci][1], r = cyc[ci][2];
      idx[p][q] = r; sgn[p][q] = 1.f;
      idx[q][p] = r; sgn[q][p] = -1.f;
    }
  }
  for (int i = 0; i < 8; ++i)
    for (int j = 0; j < 8; ++j) {
      int k = idx[i][j];
      t.J[k * 8 + i] = j;
      t.SG[k * 8 + i] = sgn[i][j];
    }
}

// workspace layout (bytes), aliased:
#define OFF_SCALES 0ull
#define OFF_WBUF   256ull
#define OFF_R16    (OFF_WBUF + 25165824ull)   // max weight = Wqkv 6144x2048 bf16
#define OFF_QKVR   (OFF_R16 + 16777216ull)
#define OFF_H      (OFF_QKVR + 50331648ull)
#define OFF_G1     (OFF_H + 33554432ull)
#define WS_NEED    (OFF_G1 + 45088768ull)     // ~163 MB

extern "C" void kernel_launch(void* const* d_in, const int* in_sizes, int n_in,
                              void* d_out, int out_size, void* d_ws, size_t ws_size,
                              hipStream_t stream) {
  (void)in_sizes; (void)n_in; (void)out_size;
  if (ws_size < WS_NEED) return;

  const float* x   = (const float*)d_in[0];
  const float* fc  = (const float*)d_in[1];
  const float* fs  = (const float*)d_in[2];
  const float* anw = (const float*)d_in[3];
  const float* fnw = (const float*)d_in[4];
  const float* wqw = (const float*)d_in[5];
  const float* wkw = (const float*)d_in[6];
  const float* wvw = (const float*)d_in[7];
  const float* wow = (const float*)d_in[8];
  const float* wgw = (const float*)d_in[9];
  const float* wuw = (const float*)d_in[10];
  const float* wdw = (const float*)d_in[11];

  char* ws = (char*)d_ws;
  float* scales = (float*)(ws + OFF_SCALES);
  bf16* Wbuf = (bf16*)(ws + OFF_WBUF);
  bf16* xn   = (bf16*)(ws + OFF_R16);   // then y, then hn
  bf16* qkv  = (bf16*)(ws + OFF_QKVR);  // then up
  float* h   = (float*)(ws + OFF_H);
  bf16* g1   = (bf16*)(ws + OFF_G1);    // gate, then act in-place

  OctTab tab; build_oct(tab);
  Ptr7 p7;
  p7.p[0] = wqw; p7.p[1] = wkw; p7.p[2] = wvw; p7.p[3] = wow;
  p7.p[4] = wgw; p7.p[5] = wuw; p7.p[6] = wdw;
  for (int i = 0; i < 4; ++i) p7.opsz[i] = 65536;
  for (int i = 4; i < 7; ++i) p7.opsz[i] = 174848;

  const float invS = 1.f / 65536.f;   // small tensors (q,k,v,o)
  const float invL = 1.f / 174848.f;  // large tensors (gate,up,down)

  scales_zero<<<1, 64, 0, stream>>>(scales);
  scales_partial<<<448, 256, 0, stream>>>(p7, scales);

  // ---- QKV: build fused [Wq;Wk;Wv] (6144x2048), gemm, rope, attention
  build_dense_kernel<<<16384, 256, 0, stream>>>(wqw, scales + 0,  invS, Wbuf, 256, 256, 2048, 0,    4194304, tab);
  build_dense_kernel<<<16384, 256, 0, stream>>>(wkw, scales + 8,  invS, Wbuf, 256, 256, 2048, 2048, 4194304, tab);
  build_dense_kernel<<<16384, 256, 0, stream>>>(wvw, scales + 16, invS, Wbuf, 256, 256, 2048, 4096, 4194304, tab);
  rmsnorm_kernel<<<4096, 256, 0, stream>>>(x, anw, xn);
  // DEPTH-3 pipeline (bold): 768 blocks, 3.0 tail-free rounds
  gemm_tile<128, 0, 2><<<dim3(24, 32), 512, 0, stream>>>(xn, Wbuf, nullptr, qkv, 2048, 6144, 6144);
  rope_kernel<<<8192, 256, 0, stream>>>(qkv, fc, fs);
  attn_kernel<<<dim3(64, 16), 256, 0, stream>>>(qkv, (bf16*)(ws + OFF_R16) /* y over xn */);

  // ---- O-proj + residual (f32): proven depth-2. K=2048.
  build_dense_kernel<<<16384, 256, 0, stream>>>(wow, scales + 24, invS, Wbuf, 256, 256, 2048, 0, 4194304, tab);
  gemm_tile<128, 1, 0><<<dim3(8, 32), 512, 0, stream>>>((bf16*)(ws + OFF_R16), Wbuf, x, h, 2048, 2048, 2048);

  // ---- FFN
  bf16* hn = (bf16*)(ws + OFF_R16);  // overwrite y (dead)
  rmsnorm_kernel<<<4096, 256, 0, stream>>>(h, fnw, hn);
  // *** A/B: gate = DEPTH-3 (SCHED 2, LDS 147456) vs up = PHASED depth-2 (SCHED 0, LDS 98304).
  // *** Identical shape/grid/A-operand -> within-probe pipeline-depth comparison.
  build_dense_kernel<<<43712, 256, 0, stream>>>(wgw, scales + 32, invL, Wbuf, 683, 256, 2048, 0, 11190272, tab);
  gemm_tile<128, 0, 2><<<dim3(22, 32), 512, 0, stream>>>(hn, Wbuf, nullptr, g1, 2048, 5504, 5504);
  // up: rebuild Wbuf, gemm -> qkv region (dead)
  bf16* up = (bf16*)(ws + OFF_QKVR);
  build_dense_kernel<<<43712, 256, 0, stream>>>(wuw, scales + 40, invL, Wbuf, 683, 256, 2048, 0, 11190272, tab);
  gemm_tile<128, 0, 0><<<dim3(22, 32), 512, 0, stream>>>(hn, Wbuf, nullptr, up, 2048, 5504, 5504);
  // silu(gate)*up -> act (in-place over gate), zeroing K-pad cols
  silu_kernel<<<11008, 256, 0, stream>>>(up, g1);
  // down: build Wd (2048x5504, zero the 40 pad cols), proven depth-2, K=5504 + residual -> out
  build_dense_kernel<<<43712, 256, 0, stream>>>(wdw, scales + 48, invL, Wbuf, 256, 683, 5504, 0, 11190272, tab);
  zero_pad_kernel<<<320, 256, 0, stream>>>(Wbuf);
  gemm_tile<128, 1, 0><<<dim3(8, 32), 512, 0, stream>>>(g1, Wbuf, h, (float*)d_out, 5504, 2048, 2048);
}